// Round 13
// baseline (475.673 us; speedup 1.0000x reference)
//
#include <hip/hip_runtime.h>

#define D_  1024
#define H_  16
#define HD_ 64
#define L_  2048
#define B_  2
#define M_  (B_*L_)   // 4096 rows

typedef float f32x4  __attribute__((ext_vector_type(4)));
typedef short bf16x4 __attribute__((ext_vector_type(4)));
typedef short bf16x8 __attribute__((ext_vector_type(8)));

#define SRAW_PITCH 18   // f32 per l-row (72B): conflict-free b64/scalar patterns
#define SRAW_SLAB  (16 * SRAW_PITCH)   // 288 f32 per h (or m) slab
#define VS_PITCH   20   // shorts per d-row (40B): 16 data + 4 pad, b64-aligned

__device__ __forceinline__ float bf2f(short s) {
    return __uint_as_float(((unsigned int)(unsigned short)s) << 16);
}
__device__ __forceinline__ short f2bf(float f) {   // RNE
    unsigned u = __float_as_uint(f);
    unsigned r = (u + 0x7FFFu + ((u >> 16) & 1u)) >> 16;
    return (short)r;
}
// Raw barrier: orders LDS (lgkmcnt(0) + "memory" clobber), does NOT drain vmcnt.
__device__ __forceinline__ void block_sync() {
    asm volatile("s_waitcnt lgkmcnt(0)" ::: "memory");
    __builtin_amdgcn_sched_barrier(0);
    __builtin_amdgcn_s_barrier();
    __builtin_amdgcn_sched_barrier(0);
}

// ---------------------------------------------------------------------------
// Kernel 1: QKV projections via bf16 MFMA. 128x128 tile, K-step 32, 256 thr.
// z=0: q -> qh(hi)+qlo  [b][h][l][64]        (A=W rows n, B=X cols m: D[n][m])
// z=1: k -> kh          [b][h][l][64]        (same)
// z=2: v -> vht         [b][h][64][L]        (A=X rows m, B=W cols n: D[m][n])
// ---------------------------------------------------------------------------
__global__ __launch_bounds__(256) void proj_mfma(
    const float* __restrict__ q, const float* __restrict__ k, const float* __restrict__ v,
    const float* __restrict__ Wq, const float* __restrict__ bq,
    const float* __restrict__ Wk, const float* __restrict__ bk,
    const float* __restrict__ Wv, const float* __restrict__ bv,
    short* __restrict__ qh, short* __restrict__ qlo,
    short* __restrict__ kh, short* __restrict__ vht)
{
    const int z = blockIdx.z;
    const float* X    = (z == 0) ? q  : (z == 1) ? k  : v;
    const float* W    = (z == 0) ? Wq : (z == 1) ? Wk : Wv;
    const float* bias = (z == 0) ? bq : (z == 1) ? bk : bv;

    __shared__ short Ws[128][40];
    __shared__ short Xs[128][40];

    const int tid  = threadIdx.x;
    const int w    = tid >> 6, lane = tid & 63;
    const int l16  = lane & 15, qq = lane >> 4;
    const int m0   = blockIdx.x * 128;
    const int n0   = blockIdx.y * 128;
    const int ar0  = 64 * (w & 1);
    const int br0  = 64 * (w >> 1);

    f32x4 acc[4][4] = {};

    for (int k0 = 0; k0 < D_; k0 += 32) {
        #pragma unroll
        for (int i = 0; i < 4; ++i) {
            int fidx = i * 256 + tid;
            int r = fidx >> 3, c = fidx & 7;
            float4 wv4 = *(const float4*)(W + (size_t)(n0 + r) * D_ + k0 + c * 4);
            float4 xv4 = *(const float4*)(X + (size_t)(m0 + r) * D_ + k0 + c * 4);
            bf16x4 wb = { f2bf(wv4.x), f2bf(wv4.y), f2bf(wv4.z), f2bf(wv4.w) };
            bf16x4 xb = { f2bf(xv4.x), f2bf(xv4.y), f2bf(xv4.z), f2bf(xv4.w) };
            *(bf16x4*)&Ws[r][c * 4] = wb;
            *(bf16x4*)&Xs[r][c * 4] = xb;
        }
        __syncthreads();
        bf16x8 af[4], bfv[4];
        #pragma unroll
        for (int i = 0; i < 4; ++i) {
            const short* Ab = (z < 2) ? &Ws[ar0 + 16 * i + l16][qq * 8]
                                      : &Xs[ar0 + 16 * i + l16][qq * 8];
            const short* Bb = (z < 2) ? &Xs[br0 + 16 * i + l16][qq * 8]
                                      : &Ws[br0 + 16 * i + l16][qq * 8];
            af[i]  = *(const bf16x8*)Ab;
            bfv[i] = *(const bf16x8*)Bb;
        }
        #pragma unroll
        for (int i = 0; i < 4; ++i)
            #pragma unroll
            for (int j = 0; j < 4; ++j)
                acc[i][j] = __builtin_amdgcn_mfma_f32_16x16x32_bf16(af[i], bfv[j], acc[i][j], 0, 0, 0);
        __syncthreads();
    }

    if (z < 2) {
        #pragma unroll
        for (int i = 0; i < 4; ++i) {
            int nb = n0 + ar0 + 16 * i + qq * 4;
            float4 b4 = *(const float4*)(bias + nb);
            int h = nb >> 6, hd = nb & 63;
            #pragma unroll
            for (int j = 0; j < 4; ++j) {
                int m = m0 + br0 + 16 * j + l16;
                int bb = m >> 11, l = m & (L_ - 1);
                size_t o = ((((size_t)bb * H_ + h) * L_) + l) * HD_ + hd;
                f32x4 c = acc[i][j];
                float v0 = c[0] + b4.x, v1 = c[1] + b4.y, v2 = c[2] + b4.z, v3 = c[3] + b4.w;
                bf16x4 hi = { f2bf(v0), f2bf(v1), f2bf(v2), f2bf(v3) };
                if (z == 0) {
                    *(bf16x4*)&qh[o] = hi;
                    bf16x4 lo = { f2bf(v0 - bf2f(hi[0])), f2bf(v1 - bf2f(hi[1])),
                                  f2bf(v2 - bf2f(hi[2])), f2bf(v3 - bf2f(hi[3])) };
                    *(bf16x4*)&qlo[o] = lo;
                } else {
                    *(bf16x4*)&kh[o] = hi;
                }
            }
        }
    } else {
        // D[m][n]: rows m = m0+ar0+16i+4qq+r ; cols n = n0+br0+16j+l16
        #pragma unroll
        for (int i = 0; i < 4; ++i) {
            int mb = m0 + ar0 + 16 * i + qq * 4;
            int bb = mb >> 11, lb = mb & (L_ - 1);
            #pragma unroll
            for (int j = 0; j < 4; ++j) {
                int n = n0 + br0 + 16 * j + l16;
                int h = n >> 6, hd = n & 63;
                float bn = bias[n];
                size_t o = (((size_t)bb * H_ + h) * HD_ + hd) * (size_t)L_ + lb;
                f32x4 c = acc[i][j];
                bf16x4 ov = { f2bf(c[0] + bn), f2bf(c[1] + bn), f2bf(c[2] + bn), f2bf(c[3] + bn) };
                *(bf16x4*)&vht[o] = ov;
            }
        }
    }
}

// ---------------------------------------------------------------------------
// Kernel 2: fused talking-heads attention, m-SPLIT (flash split-K).
// Grid = 256 * nsplit blocks; block n: half = n>>8, covers ntiles m-tiles.
// 512 thr (8 waves). LDS 78.8 KB -> 2 blocks/CU -> 4 waves/SIMD (the point).
// KVBLK=16, single Sraw + single Smix (R12 2-barrier WAR scheme), slim Vslab.
// Epilogue: pacc!=null -> write unnormalized partials + (m,s); else direct.
// ---------------------------------------------------------------------------
__global__ __launch_bounds__(512, 4) void attn_mfma(
    const short* __restrict__ qh, const short* __restrict__ qlo,
    const short* __restrict__ kh, const short* __restrict__ vht,
    const float* __restrict__ P, short* __restrict__ attn_out,
    float* __restrict__ pacc, float* __restrict__ pms, int ntiles)
{
    __shared__ __align__(16) float Sraw[16 * SRAW_SLAB];          // [h][l][18] 18.4 KB
    __shared__ __align__(16) float Smix[16 * SRAW_SLAB];          // [m][l][18] 18.4 KB
    __shared__ __align__(16) short Vslab[8][2 * 64 * VS_PITCH];   // 40.9 KB
    __shared__ float PmS[256];

    const int tid  = threadIdx.x;
    const int n    = blockIdx.x;
    const int half = n >> 8;
    const int inr  = n & 255;
    const int b    = (inr >> 2) & 1;                      // XCD swizzle
    const int l0   = ((inr >> 3) * 4 + (inr & 3)) * 16;
    const int tb   = half * ntiles;                       // first m-tile
    const int w    = tid >> 6, lane = tid & 63;
    const int l16  = lane & 15, qq = lane >> 4;
    const size_t hb = (size_t)b * H_;

    // ---- Q frags (persistent)
    bf16x8 qf[2][2][2];
    #pragma unroll
    for (int hh = 0; hh < 2; ++hh)
        #pragma unroll
        for (int kc = 0; kc < 2; ++kc) {
            size_t off = ((hb + 2 * w + hh) * L_ + l0 + l16) * HD_ + kc * 32 + qq * 8;
            qf[hh][kc][0] = *(const bf16x8*)(qh  + off);
            qf[hh][kc][1] = *(const bf16x8*)(qlo + off);
        }

    // V^T staging mapping
    int vgi_[4], vd_[4];
    const int vc = lane & 1;
    #pragma unroll
    for (int i = 0; i < 4; ++i) {
        int vrow = i * 32 + (lane >> 1);
        vgi_[i] = vrow >> 6;
        vd_[i]  = vrow & 63;
    }
    int vwoff[4];
    #pragma unroll
    for (int i = 0; i < 4; ++i)
        vwoff[i] = vgi_[i] * (64 * VS_PITCH) + vd_[i] * VS_PITCH + vc * 8;

    auto kload = [&](int tile, bf16x8 (&kdst)[2][2]) {
        const int mn = (tile & 127) * 16;
        #pragma unroll
        for (int hh = 0; hh < 2; ++hh)
            #pragma unroll
            for (int kc = 0; kc < 2; ++kc)
                kdst[hh][kc] = *(const bf16x8*)(kh + ((hb + 2 * w + hh) * L_ + mn + l16) * HD_ + kc * 32 + qq * 8);
    };
    auto vload = [&](int tile, bf16x8 (&vdst)[4]) {
        const int mn = (tile & 127) * 16;
        #pragma unroll
        for (int i = 0; i < 4; ++i)
            vdst[i] = *(const bf16x8*)(vht + ((hb + 2 * w + vgi_[i]) * HD_ + vd_[i]) * (size_t)L_ + mn + vc * 8);
    };

    bf16x8 kP[2][2], vst[4];
    kload(tb, kP); vload(tb, vst);

    if (tid < 256) PmS[tid] = P[tid] * 0.125f;            // fold 1/sqrt(64)

    f32x4 acc[2][4];
    #pragma unroll
    for (int dt = 0; dt < 4; ++dt) { acc[0][dt] = (f32x4){0.f,0.f,0.f,0.f}; acc[1][dt] = (f32x4){0.f,0.f,0.f,0.f}; }
    float mrun0 = 0.f, mrun1 = 0.f, srun0 = 0.f, srun1 = 0.f;   // deferred-max

    // QK^T: D[m][l], col=l16, rows m=qq*4+j.
    auto qkt = [&](bf16x8 (&kr)[2][2], float* sb) {
        #pragma unroll
        for (int hh = 0; hh < 2; ++hh) {
            f32x4 s = (f32x4){0.f,0.f,0.f,0.f};
            s = __builtin_amdgcn_mfma_f32_16x16x32_bf16(kr[hh][0], qf[hh][0][0], s, 0, 0, 0);
            s = __builtin_amdgcn_mfma_f32_16x16x32_bf16(kr[hh][0], qf[hh][0][1], s, 0, 0, 0);
            s = __builtin_amdgcn_mfma_f32_16x16x32_bf16(kr[hh][1], qf[hh][1][0], s, 0, 0, 0);
            s = __builtin_amdgcn_mfma_f32_16x16x32_bf16(kr[hh][1], qf[hh][1][1], s, 0, 0, 0);
            float* sp = sb + ((2 * w + hh) * 16 + l16) * SRAW_PITCH + qq * 4;
            *(float2*)sp       = make_float2(s[0], s[1]);
            *(float2*)(sp + 2) = make_float2(s[2], s[3]);
        }
    };

    // prologue: QK^T(tile tb) -> Sraw, publish (also PmS)
    qkt(kP, Sraw);
    block_sync();
    kload(tb + 1, kP);

    bf16x4 PAhi, PAlo;
    {
        float p0 = PmS[(qq * 4 + 0) * 16 + l16];
        float p1 = PmS[(qq * 4 + 1) * 16 + l16];
        float p2 = PmS[(qq * 4 + 2) * 16 + l16];
        float p3 = PmS[(qq * 4 + 3) * 16 + l16];
        PAhi = (bf16x4){ f2bf(p0), f2bf(p1), f2bf(p2), f2bf(p3) };
        PAlo = (bf16x4){ f2bf(p0 - bf2f(PAhi[0])), f2bf(p1 - bf2f(PAhi[1])),
                         f2bf(p2 - bf2f(PAhi[2])), f2bf(p3 - bf2f(PAhi[3])) };
    }

    for (int t = 0; t < ntiles; ++t) {
        // 1. mix via MFMA: B = scalar-gathered S hi/lo -> Smix[m][l][g]
        #pragma unroll
        for (int mi = 0; mi < 2; ++mi) {
            const int m = 2 * w + mi;
            float sv0 = Sraw[(qq * 4 + 0) * SRAW_SLAB + l16 * SRAW_PITCH + m];
            float sv1 = Sraw[(qq * 4 + 1) * SRAW_SLAB + l16 * SRAW_PITCH + m];
            float sv2 = Sraw[(qq * 4 + 2) * SRAW_SLAB + l16 * SRAW_PITCH + m];
            float sv3 = Sraw[(qq * 4 + 3) * SRAW_SLAB + l16 * SRAW_PITCH + m];
            bf16x4 bhi = { f2bf(sv0), f2bf(sv1), f2bf(sv2), f2bf(sv3) };
            bf16x4 blo = { f2bf(sv0 - bf2f(bhi[0])), f2bf(sv1 - bf2f(bhi[1])),
                           f2bf(sv2 - bf2f(bhi[2])), f2bf(sv3 - bf2f(bhi[3])) };
            f32x4 c = (f32x4){0.f, 0.f, 0.f, 0.f};
            c = __builtin_amdgcn_mfma_f32_16x16x16bf16_1k(PAhi, bhi, c, 0, 0, 0);
            c = __builtin_amdgcn_mfma_f32_16x16x16bf16_1k(PAhi, blo, c, 0, 0, 0);
            c = __builtin_amdgcn_mfma_f32_16x16x16bf16_1k(PAlo, bhi, c, 0, 0, 0);
            float* sp = Smix + m * SRAW_SLAB + l16 * SRAW_PITCH + qq * 4;
            *(float2*)sp       = make_float2(c[0], c[1]);
            *(float2*)(sp + 2) = make_float2(c[2], c[3]);
        }
        block_sync();   // B_mid: Smix visible; mix-reads of Sraw done
        // 2. QK^T(tile tb+t+1) -> Sraw (safe: all mix-reads complete)
        qkt(kP, Sraw);
        kload(tb + t + 2, kP);
        // 3. softmax inputs from Smix
        float sx0[4], sx1[4];
        #pragma unroll
        for (int j = 0; j < 4; ++j) {
            const float* mp = Smix + (qq * 4 + j) * SRAW_SLAB + l16 * SRAW_PITCH;
            sx0[j] = mp[2 * w];
            sx1[j] = mp[2 * w + 1];
        }
        // 4. deferred-max exps
        float e00 = __expf(sx0[0] - mrun0), e01 = __expf(sx0[1] - mrun0);
        float e02 = __expf(sx0[2] - mrun0), e03 = __expf(sx0[3] - mrun0);
        float e10 = __expf(sx1[0] - mrun1), e11 = __expf(sx1[1] - mrun1);
        float e12 = __expf(sx1[2] - mrun1), e13 = __expf(sx1[3] - mrun1);
        bf16x4 pf0 = { f2bf(e00), f2bf(e01), f2bf(e02), f2bf(e03) };
        bf16x4 pf1 = { f2bf(e10), f2bf(e11), f2bf(e12), f2bf(e13) };
        float t0r = fmaxf(fmaxf(sx0[0], sx0[1]), fmaxf(sx0[2], sx0[3]));
        float t1r = fmaxf(fmaxf(sx1[0], sx1[1]), fmaxf(sx1[2], sx1[3]));
        t0r = fmaxf(t0r, __shfl_xor(t0r, 16)); t0r = fmaxf(t0r, __shfl_xor(t0r, 32));
        t1r = fmaxf(t1r, __shfl_xor(t1r, 16)); t1r = fmaxf(t1r, __shfl_xor(t1r, 32));
        float ps0 = e00 + e01 + e02 + e03, ps1 = e10 + e11 + e12 + e13;
        ps0 += __shfl_xor(ps0, 16); ps0 += __shfl_xor(ps0, 32);
        ps1 += __shfl_xor(ps1, 16); ps1 += __shfl_xor(ps1, 32);
        // 5. stage V + PV (same-wave slab, DS in-order)
        #pragma unroll
        for (int i = 0; i < 4; ++i) {
            bf16x4 wlo = { vst[i][0], vst[i][1], vst[i][2], vst[i][3] };
            bf16x4 whi = { vst[i][4], vst[i][5], vst[i][6], vst[i][7] };
            *(bf16x4*)&Vslab[w][vwoff[i]]     = wlo;
            *(bf16x4*)&Vslab[w][vwoff[i] + 4] = whi;
        }
        #pragma unroll
        for (int i = 0; i < 2; ++i) {
            bf16x4 pf = i ? pf1 : pf0;
            #pragma unroll
            for (int dt = 0; dt < 4; ++dt) {
                bf16x4 afr = *(const bf16x4*)&Vslab[w][i * (64 * VS_PITCH) + (dt * 16 + l16) * VS_PITCH + qq * 4];
                acc[i][dt] = __builtin_amdgcn_mfma_f32_16x16x16bf16_1k(afr, pf, acc[i][dt], 0, 0, 0);
            }
        }
        // 6. V refill (vst dead after PV)
        vload(tb + t + 1, vst);
        // 7. rescale to new running max
        float mnew0 = fmaxf(mrun0, t0r), mnew1 = fmaxf(mrun1, t1r);
        float corr0 = __expf(mrun0 - mnew0), corr1 = __expf(mrun1 - mnew1);
        srun0 = (srun0 + ps0) * corr0; srun1 = (srun1 + ps1) * corr1;
        acc[0][0] *= corr0; acc[0][1] *= corr0; acc[0][2] *= corr0; acc[0][3] *= corr0;
        acc[1][0] *= corr1; acc[1][1] *= corr1; acc[1][2] *= corr1; acc[1][3] *= corr1;
        mrun0 = mnew0; mrun1 = mnew1;
        block_sync();   // B_end: Smix reads done; Sraw(t+1) published
    }

    if (pacc) {
        // partial epilogue: unnormalized acc + (m, s) per (g, l)
        #pragma unroll
        for (int i = 0; i < 2; ++i) {
            int g = 2 * w + i;
            #pragma unroll
            for (int dt = 0; dt < 4; ++dt)
                *(f32x4*)&pacc[(((size_t)n * 16 + g) * 16 + l16) * 64 + dt * 16 + qq * 4] = acc[i][dt];
        }
        if (qq == 0) {
            *(float2*)&pms[(((size_t)n * 16 + 2 * w)     * 16 + l16) * 2] = make_float2(mrun0, srun0);
            *(float2*)&pms[(((size_t)n * 16 + 2 * w + 1) * 16 + l16) * 2] = make_float2(mrun1, srun1);
        }
    } else {
        float inv0 = 1.f / srun0, inv1 = 1.f / srun1;
        #pragma unroll
        for (int i = 0; i < 2; ++i) {
            float inv = i ? inv1 : inv0;
            #pragma unroll
            for (int dt = 0; dt < 4; ++dt) {
                f32x4 a = acc[i][dt];
                bf16x4 ov = { f2bf(a[0] * inv), f2bf(a[1] * inv), f2bf(a[2] * inv), f2bf(a[3] * inv) };
                *(bf16x4*)(attn_out + ((size_t)(b * L_ + l0 + l16)) * D_ + (2 * w + i) * 64 + dt * 16 + qq * 4) = ov;
            }
        }
    }
}

// ---------------------------------------------------------------------------
// Kernel 2b: merge the 2 m-split partials -> bf16 attn.
// thread -> one f32x4 chunk: cid = (b, l, g, d4)
// ---------------------------------------------------------------------------
__global__ __launch_bounds__(256) void merge_attn(
    const float* __restrict__ pacc, const float* __restrict__ pms,
    short* __restrict__ attn)
{
    const int cid = blockIdx.x * 256 + threadIdx.x;
    const int d4 = cid & 15;
    const int g  = (cid >> 4) & 15;
    const int l  = (cid >> 8) & (L_ - 1);
    const int b  = cid >> 19;
    const int lt = l >> 4, l16 = l & 15;
    const int n0 = ((lt >> 2) << 3) + (b << 2) + (lt & 3);
    const int n1 = n0 + 256;

    float2 ms0 = *(const float2*)&pms[(((size_t)n0 * 16 + g) * 16 + l16) * 2];
    float2 ms1 = *(const float2*)&pms[(((size_t)n1 * 16 + g) * 16 + l16) * 2];
    f32x4 o0 = *(const f32x4*)&pacc[(((size_t)n0 * 16 + g) * 16 + l16) * 64 + d4 * 4];
    f32x4 o1 = *(const f32x4*)&pacc[(((size_t)n1 * 16 + g) * 16 + l16) * 64 + d4 * 4];
    float Mx = fmaxf(ms0.x, ms1.x);
    float w0 = __expf(ms0.x - Mx), w1 = __expf(ms1.x - Mx);
    float s = ms0.y * w0 + ms1.y * w1;
    float inv = 1.f / s;
    f32x4 o = o0 * w0 + o1 * w1;
    bf16x4 ov = { f2bf(o[0] * inv), f2bf(o[1] * inv), f2bf(o[2] * inv), f2bf(o[3] * inv) };
    *(bf16x4*)(attn + ((size_t)(b * L_ + l) * D_) + g * 64 + d4 * 4) = ov;
}

// ---------------------------------------------------------------------------
// Kernel 3: output projection (attn bf16 @ Wo^T + bo) -> f32, MFMA.
// ---------------------------------------------------------------------------
__global__ __launch_bounds__(256) void out_mfma(
    const short* __restrict__ attn, const float* __restrict__ Wo,
    const float* __restrict__ bo, float* __restrict__ out)
{
    __shared__ short Ws[128][40];
    __shared__ short Xs[128][40];

    const int tid = threadIdx.x;
    const int w = tid >> 6, lane = tid & 63;
    const int l16 = lane & 15, qq = lane >> 4;
    const int m0 = blockIdx.x * 128;
    const int n0 = blockIdx.y * 128;
    const int ar0 = 64 * (w & 1);
    const int br0 = 64 * (w >> 1);

    f32x4 acc[4][4] = {};

    for (int k0 = 0; k0 < D_; k0 += 32) {
        #pragma unroll
        for (int i = 0; i < 4; ++i) {
            int fidx = i * 256 + tid;
            int r = fidx >> 3, c = fidx & 7;
            float4 wv4 = *(const float4*)(Wo + (size_t)(n0 + r) * D_ + k0 + c * 4);
            bf16x4 wb = { f2bf(wv4.x), f2bf(wv4.y), f2bf(wv4.z), f2bf(wv4.w) };
            *(bf16x4*)&Ws[r][c * 4] = wb;
        }
        #pragma unroll
        for (int i = 0; i < 2; ++i) {
            int cidx = i * 256 + tid;
            int r = cidx >> 2, c = cidx & 3;
            bf16x8 xv = *(const bf16x8*)(attn + (size_t)(m0 + r) * D_ + k0 + c * 8);
            *(bf16x8*)&Xs[r][c * 8] = xv;
        }
        __syncthreads();
        bf16x8 af[4], bfv[4];
        #pragma unroll
        for (int i = 0; i < 4; ++i) {
            af[i]  = *(const bf16x8*)&Ws[ar0 + 16 * i + l16][qq * 8];
            bfv[i] = *(const bf16x8*)&Xs[br0 + 16 * i + l16][qq * 8];
        }
        #pragma unroll
        for (int i = 0; i < 4; ++i)
            #pragma unroll
            for (int j = 0; j < 4; ++j)
                acc[i][j] = __builtin_amdgcn_mfma_f32_16x16x32_bf16(af[i], bfv[j], acc[i][j], 0, 0, 0);
        __syncthreads();
    }

    #pragma unroll
    for (int i = 0; i < 4; ++i) {
        int nb = n0 + ar0 + 16 * i + qq * 4;
        float4 b4 = *(const float4*)(bo + nb);
        #pragma unroll
        for (int j = 0; j < 4; ++j) {
            int m = m0 + br0 + 16 * j + l16;
            f32x4 c = acc[i][j];
            float4 ov = make_float4(c[0] + b4.x, c[1] + b4.y, c[2] + b4.z, c[3] + b4.w);
            *(float4*)&out[(size_t)m * D_ + nb] = ov;
        }
    }
}

// ---------------------------------------------------------------------------
extern "C" void kernel_launch(void* const* d_in, const int* in_sizes, int n_in,
                              void* d_out, int out_size, void* d_ws, size_t ws_size,
                              hipStream_t stream) {
    const float* q  = (const float*)d_in[0];
    const float* k  = (const float*)d_in[1];
    const float* v  = (const float*)d_in[2];
    const float* Wq = (const float*)d_in[3];
    const float* bq = (const float*)d_in[4];
    const float* Wk = (const float*)d_in[5];
    const float* bk = (const float*)d_in[6];
    const float* Wv = (const float*)d_in[7];
    const float* bv = (const float*)d_in[8];
    const float* Wo = (const float*)d_in[9];
    const float* bo = (const float*)d_in[10];
    const float* P  = (const float*)d_in[11];
    float* out = (float*)d_out;

    // ws: qh 8M | qlo 8M | kh 8M | vht 8M | attn 8M | pacc 32MiB | pms 1MiB
    char* ws = (char*)d_ws;
    short* qh   = (short*)(ws);
    short* qlo  = (short*)(ws + (size_t)8 * 1024 * 1024);
    short* kh   = (short*)(ws + (size_t)16 * 1024 * 1024);
    short* vht  = (short*)(ws + (size_t)24 * 1024 * 1024);
    short* attn = (short*)(ws + (size_t)32 * 1024 * 1024);
    float* pacc = (float*)(ws + (size_t)40 * 1024 * 1024);
    float* pms  = (float*)(ws + (size_t)40 * 1024 * 1024 + (size_t)512 * 16 * 16 * 64 * 4);
    const size_t need2 = (size_t)40 * 1024 * 1024
                       + (size_t)512 * 16 * 16 * 64 * 4    // pacc 32 MiB
                       + (size_t)512 * 16 * 16 * 2 * 4;    // pms 1 MiB
    const bool split2 = (ws_size >= need2);

    proj_mfma<<<dim3(M_ / 128, D_ / 128, 3), 256, 0, stream>>>(
        q, k, v, Wq, bq, Wk, bk, Wv, bv, qh, qlo, kh, vht);
    if (split2) {
        attn_mfma<<<dim3(512), 512, 0, stream>>>(qh, qlo, kh, vht, P, attn, pacc, pms, 64);
        merge_attn<<<dim3(4096), 256, 0, stream>>>(pacc, pms, attn);
    } else {
        attn_mfma<<<dim3(256), 512, 0, stream>>>(qh, qlo, kh, vht, P, attn, nullptr, nullptr, 128);
    }
    out_mfma<<<dim3(M_ / 128, D_ / 128), 256, 0, stream>>>(attn, Wo, bo, out);
}

// Round 14
// 387.648 us; speedup vs baseline: 1.2271x; 1.2271x over previous
//
#include <hip/hip_runtime.h>

#define D_  1024
#define H_  16
#define HD_ 64
#define L_  2048
#define B_  2
#define M_  (B_*L_)   // 4096 rows

typedef float f32x4  __attribute__((ext_vector_type(4)));
typedef short bf16x4 __attribute__((ext_vector_type(4)));
typedef short bf16x8 __attribute__((ext_vector_type(8)));

#define SRAW_PITCH 18   // f32 per l-row (72B): conflict-free b64/scalar patterns
#define SRAW_SLAB  (16 * SRAW_PITCH)   // 288 f32 per h (or m) slab
#define VS_PITCH   20   // shorts per d-row (40B): 16 data + 4 pad, b64-aligned

__device__ __forceinline__ float bf2f(short s) {
    return __uint_as_float(((unsigned int)(unsigned short)s) << 16);
}
__device__ __forceinline__ short f2bf(float f) {   // RNE
    unsigned u = __float_as_uint(f);
    unsigned r = (u + 0x7FFFu + ((u >> 16) & 1u)) >> 16;
    return (short)r;
}
// Raw barrier: orders LDS (lgkmcnt(0) + "memory" clobber), does NOT drain vmcnt.
__device__ __forceinline__ void block_sync() {
    asm volatile("s_waitcnt lgkmcnt(0)" ::: "memory");
    __builtin_amdgcn_sched_barrier(0);
    __builtin_amdgcn_s_barrier();
    __builtin_amdgcn_sched_barrier(0);
}

// ---------------------------------------------------------------------------
// Kernel 1: QKV projections via bf16 MFMA. 128x128 tile, K-step 32, 256 thr.
// z=0: q -> qh(hi)+qlo  [b][h][l][64]        (A=W rows n, B=X cols m: D[n][m])
// z=1: k -> kh          [b][h][l][64]        (same)
// z=2: v -> vht         [b][h][64][L]        (A=X rows m, B=W cols n: D[m][n])
// ---------------------------------------------------------------------------
__global__ __launch_bounds__(256) void proj_mfma(
    const float* __restrict__ q, const float* __restrict__ k, const float* __restrict__ v,
    const float* __restrict__ Wq, const float* __restrict__ bq,
    const float* __restrict__ Wk, const float* __restrict__ bk,
    const float* __restrict__ Wv, const float* __restrict__ bv,
    short* __restrict__ qh, short* __restrict__ qlo,
    short* __restrict__ kh, short* __restrict__ vht)
{
    const int z = blockIdx.z;
    const float* X    = (z == 0) ? q  : (z == 1) ? k  : v;
    const float* W    = (z == 0) ? Wq : (z == 1) ? Wk : Wv;
    const float* bias = (z == 0) ? bq : (z == 1) ? bk : bv;

    __shared__ short Ws[128][40];
    __shared__ short Xs[128][40];

    const int tid  = threadIdx.x;
    const int w    = tid >> 6, lane = tid & 63;
    const int l16  = lane & 15, qq = lane >> 4;
    const int m0   = blockIdx.x * 128;
    const int n0   = blockIdx.y * 128;
    const int ar0  = 64 * (w & 1);
    const int br0  = 64 * (w >> 1);

    f32x4 acc[4][4] = {};

    for (int k0 = 0; k0 < D_; k0 += 32) {
        #pragma unroll
        for (int i = 0; i < 4; ++i) {
            int fidx = i * 256 + tid;
            int r = fidx >> 3, c = fidx & 7;
            float4 wv4 = *(const float4*)(W + (size_t)(n0 + r) * D_ + k0 + c * 4);
            float4 xv4 = *(const float4*)(X + (size_t)(m0 + r) * D_ + k0 + c * 4);
            bf16x4 wb = { f2bf(wv4.x), f2bf(wv4.y), f2bf(wv4.z), f2bf(wv4.w) };
            bf16x4 xb = { f2bf(xv4.x), f2bf(xv4.y), f2bf(xv4.z), f2bf(xv4.w) };
            *(bf16x4*)&Ws[r][c * 4] = wb;
            *(bf16x4*)&Xs[r][c * 4] = xb;
        }
        __syncthreads();
        bf16x8 af[4], bfv[4];
        #pragma unroll
        for (int i = 0; i < 4; ++i) {
            const short* Ab = (z < 2) ? &Ws[ar0 + 16 * i + l16][qq * 8]
                                      : &Xs[ar0 + 16 * i + l16][qq * 8];
            const short* Bb = (z < 2) ? &Xs[br0 + 16 * i + l16][qq * 8]
                                      : &Ws[br0 + 16 * i + l16][qq * 8];
            af[i]  = *(const bf16x8*)Ab;
            bfv[i] = *(const bf16x8*)Bb;
        }
        #pragma unroll
        for (int i = 0; i < 4; ++i)
            #pragma unroll
            for (int j = 0; j < 4; ++j)
                acc[i][j] = __builtin_amdgcn_mfma_f32_16x16x32_bf16(af[i], bfv[j], acc[i][j], 0, 0, 0);
        __syncthreads();
    }

    if (z < 2) {
        #pragma unroll
        for (int i = 0; i < 4; ++i) {
            int nb = n0 + ar0 + 16 * i + qq * 4;
            float4 b4 = *(const float4*)(bias + nb);
            int h = nb >> 6, hd = nb & 63;
            #pragma unroll
            for (int j = 0; j < 4; ++j) {
                int m = m0 + br0 + 16 * j + l16;
                int bb = m >> 11, l = m & (L_ - 1);
                size_t o = ((((size_t)bb * H_ + h) * L_) + l) * HD_ + hd;
                f32x4 c = acc[i][j];
                float v0 = c[0] + b4.x, v1 = c[1] + b4.y, v2 = c[2] + b4.z, v3 = c[3] + b4.w;
                bf16x4 hi = { f2bf(v0), f2bf(v1), f2bf(v2), f2bf(v3) };
                if (z == 0) {
                    *(bf16x4*)&qh[o] = hi;
                    bf16x4 lo = { f2bf(v0 - bf2f(hi[0])), f2bf(v1 - bf2f(hi[1])),
                                  f2bf(v2 - bf2f(hi[2])), f2bf(v3 - bf2f(hi[3])) };
                    *(bf16x4*)&qlo[o] = lo;
                } else {
                    *(bf16x4*)&kh[o] = hi;
                }
            }
        }
    } else {
        // D[m][n]: rows m = m0+ar0+16i+4qq+r ; cols n = n0+br0+16j+l16
        #pragma unroll
        for (int i = 0; i < 4; ++i) {
            int mb = m0 + ar0 + 16 * i + qq * 4;
            int bb = mb >> 11, lb = mb & (L_ - 1);
            #pragma unroll
            for (int j = 0; j < 4; ++j) {
                int n = n0 + br0 + 16 * j + l16;
                int h = n >> 6, hd = n & 63;
                float bn = bias[n];
                size_t o = (((size_t)bb * H_ + h) * HD_ + hd) * (size_t)L_ + lb;
                f32x4 c = acc[i][j];
                bf16x4 ov = { f2bf(c[0] + bn), f2bf(c[1] + bn), f2bf(c[2] + bn), f2bf(c[3] + bn) };
                *(bf16x4*)&vht[o] = ov;
            }
        }
    }
}

// ---------------------------------------------------------------------------
// Kernel 2: fused talking-heads attention, m-SPLIT (flash split-K).
// Grid = 256 * nsplit blocks; block n: half = n>>8, covers ntiles m-tiles.
// 512 thr (8 waves). LDS 78.8 KB -> 2 blocks/CU via LDS budget.
// R14: launch_bounds (512,2) -- R13's (512,4) capped VGPR at 64 -> spills
// (FETCH/WRITE +50MB, HBM 306 GB/s). Expect ~112 VGPR: 16 waves x 112 = 448
// per SIMD <= 512, so 2 blocks/CU still resident, now spill-free.
// ---------------------------------------------------------------------------
__global__ __launch_bounds__(512, 2) void attn_mfma(
    const short* __restrict__ qh, const short* __restrict__ qlo,
    const short* __restrict__ kh, const short* __restrict__ vht,
    const float* __restrict__ P, short* __restrict__ attn_out,
    float* __restrict__ pacc, float* __restrict__ pms, int ntiles)
{
    __shared__ __align__(16) float Sraw[16 * SRAW_SLAB];          // [h][l][18] 18.4 KB
    __shared__ __align__(16) float Smix[16 * SRAW_SLAB];          // [m][l][18] 18.4 KB
    __shared__ __align__(16) short Vslab[8][2 * 64 * VS_PITCH];   // 40.9 KB
    __shared__ float PmS[256];

    const int tid  = threadIdx.x;
    const int n    = blockIdx.x;
    const int half = n >> 8;
    const int inr  = n & 255;
    const int b    = (inr >> 2) & 1;                      // XCD swizzle
    const int l0   = ((inr >> 3) * 4 + (inr & 3)) * 16;
    const int tb   = half * ntiles;                       // first m-tile
    const int w    = tid >> 6, lane = tid & 63;
    const int l16  = lane & 15, qq = lane >> 4;
    const size_t hb = (size_t)b * H_;

    // ---- Q frags (persistent)
    bf16x8 qf[2][2][2];
    #pragma unroll
    for (int hh = 0; hh < 2; ++hh)
        #pragma unroll
        for (int kc = 0; kc < 2; ++kc) {
            size_t off = ((hb + 2 * w + hh) * L_ + l0 + l16) * HD_ + kc * 32 + qq * 8;
            qf[hh][kc][0] = *(const bf16x8*)(qh  + off);
            qf[hh][kc][1] = *(const bf16x8*)(qlo + off);
        }

    // V^T staging mapping
    int vgi_[4], vd_[4];
    const int vc = lane & 1;
    #pragma unroll
    for (int i = 0; i < 4; ++i) {
        int vrow = i * 32 + (lane >> 1);
        vgi_[i] = vrow >> 6;
        vd_[i]  = vrow & 63;
    }
    int vwoff[4];
    #pragma unroll
    for (int i = 0; i < 4; ++i)
        vwoff[i] = vgi_[i] * (64 * VS_PITCH) + vd_[i] * VS_PITCH + vc * 8;

    auto kload = [&](int tile, bf16x8 (&kdst)[2][2]) {
        const int mn = (tile & 127) * 16;
        #pragma unroll
        for (int hh = 0; hh < 2; ++hh)
            #pragma unroll
            for (int kc = 0; kc < 2; ++kc)
                kdst[hh][kc] = *(const bf16x8*)(kh + ((hb + 2 * w + hh) * L_ + mn + l16) * HD_ + kc * 32 + qq * 8);
    };
    auto vload = [&](int tile, bf16x8 (&vdst)[4]) {
        const int mn = (tile & 127) * 16;
        #pragma unroll
        for (int i = 0; i < 4; ++i)
            vdst[i] = *(const bf16x8*)(vht + ((hb + 2 * w + vgi_[i]) * HD_ + vd_[i]) * (size_t)L_ + mn + vc * 8);
    };

    bf16x8 kP[2][2], vst[4];
    kload(tb, kP); vload(tb, vst);

    if (tid < 256) PmS[tid] = P[tid] * 0.125f;            // fold 1/sqrt(64)

    f32x4 acc[2][4];
    #pragma unroll
    for (int dt = 0; dt < 4; ++dt) { acc[0][dt] = (f32x4){0.f,0.f,0.f,0.f}; acc[1][dt] = (f32x4){0.f,0.f,0.f,0.f}; }
    float mrun0 = 0.f, mrun1 = 0.f, srun0 = 0.f, srun1 = 0.f;   // deferred-max

    // QK^T: D[m][l], col=l16, rows m=qq*4+j.
    auto qkt = [&](bf16x8 (&kr)[2][2], float* sb) {
        #pragma unroll
        for (int hh = 0; hh < 2; ++hh) {
            f32x4 s = (f32x4){0.f,0.f,0.f,0.f};
            s = __builtin_amdgcn_mfma_f32_16x16x32_bf16(kr[hh][0], qf[hh][0][0], s, 0, 0, 0);
            s = __builtin_amdgcn_mfma_f32_16x16x32_bf16(kr[hh][0], qf[hh][0][1], s, 0, 0, 0);
            s = __builtin_amdgcn_mfma_f32_16x16x32_bf16(kr[hh][1], qf[hh][1][0], s, 0, 0, 0);
            s = __builtin_amdgcn_mfma_f32_16x16x32_bf16(kr[hh][1], qf[hh][1][1], s, 0, 0, 0);
            float* sp = sb + ((2 * w + hh) * 16 + l16) * SRAW_PITCH + qq * 4;
            *(float2*)sp       = make_float2(s[0], s[1]);
            *(float2*)(sp + 2) = make_float2(s[2], s[3]);
        }
    };

    // prologue: QK^T(tile tb) -> Sraw, publish (also PmS)
    qkt(kP, Sraw);
    block_sync();
    kload(tb + 1, kP);

    bf16x4 PAhi, PAlo;
    {
        float p0 = PmS[(qq * 4 + 0) * 16 + l16];
        float p1 = PmS[(qq * 4 + 1) * 16 + l16];
        float p2 = PmS[(qq * 4 + 2) * 16 + l16];
        float p3 = PmS[(qq * 4 + 3) * 16 + l16];
        PAhi = (bf16x4){ f2bf(p0), f2bf(p1), f2bf(p2), f2bf(p3) };
        PAlo = (bf16x4){ f2bf(p0 - bf2f(PAhi[0])), f2bf(p1 - bf2f(PAhi[1])),
                         f2bf(p2 - bf2f(PAhi[2])), f2bf(p3 - bf2f(PAhi[3])) };
    }

    for (int t = 0; t < ntiles; ++t) {
        // 1. mix via MFMA: B = scalar-gathered S hi/lo -> Smix[m][l][g]
        #pragma unroll
        for (int mi = 0; mi < 2; ++mi) {
            const int m = 2 * w + mi;
            float sv0 = Sraw[(qq * 4 + 0) * SRAW_SLAB + l16 * SRAW_PITCH + m];
            float sv1 = Sraw[(qq * 4 + 1) * SRAW_SLAB + l16 * SRAW_PITCH + m];
            float sv2 = Sraw[(qq * 4 + 2) * SRAW_SLAB + l16 * SRAW_PITCH + m];
            float sv3 = Sraw[(qq * 4 + 3) * SRAW_SLAB + l16 * SRAW_PITCH + m];
            bf16x4 bhi = { f2bf(sv0), f2bf(sv1), f2bf(sv2), f2bf(sv3) };
            bf16x4 blo = { f2bf(sv0 - bf2f(bhi[0])), f2bf(sv1 - bf2f(bhi[1])),
                           f2bf(sv2 - bf2f(bhi[2])), f2bf(sv3 - bf2f(bhi[3])) };
            f32x4 c = (f32x4){0.f, 0.f, 0.f, 0.f};
            c = __builtin_amdgcn_mfma_f32_16x16x16bf16_1k(PAhi, bhi, c, 0, 0, 0);
            c = __builtin_amdgcn_mfma_f32_16x16x16bf16_1k(PAhi, blo, c, 0, 0, 0);
            c = __builtin_amdgcn_mfma_f32_16x16x16bf16_1k(PAlo, bhi, c, 0, 0, 0);
            float* sp = Smix + m * SRAW_SLAB + l16 * SRAW_PITCH + qq * 4;
            *(float2*)sp       = make_float2(c[0], c[1]);
            *(float2*)(sp + 2) = make_float2(c[2], c[3]);
        }
        block_sync();   // B_mid: Smix visible; mix-reads of Sraw done
        // 2. QK^T(tile tb+t+1) -> Sraw (safe: all mix-reads complete)
        qkt(kP, Sraw);
        kload(tb + t + 2, kP);
        // 3. softmax inputs from Smix
        float sx0[4], sx1[4];
        #pragma unroll
        for (int j = 0; j < 4; ++j) {
            const float* mp = Smix + (qq * 4 + j) * SRAW_SLAB + l16 * SRAW_PITCH;
            sx0[j] = mp[2 * w];
            sx1[j] = mp[2 * w + 1];
        }
        // 4. deferred-max exps
        float e00 = __expf(sx0[0] - mrun0), e01 = __expf(sx0[1] - mrun0);
        float e02 = __expf(sx0[2] - mrun0), e03 = __expf(sx0[3] - mrun0);
        float e10 = __expf(sx1[0] - mrun1), e11 = __expf(sx1[1] - mrun1);
        float e12 = __expf(sx1[2] - mrun1), e13 = __expf(sx1[3] - mrun1);
        bf16x4 pf0 = { f2bf(e00), f2bf(e01), f2bf(e02), f2bf(e03) };
        bf16x4 pf1 = { f2bf(e10), f2bf(e11), f2bf(e12), f2bf(e13) };
        float t0r = fmaxf(fmaxf(sx0[0], sx0[1]), fmaxf(sx0[2], sx0[3]));
        float t1r = fmaxf(fmaxf(sx1[0], sx1[1]), fmaxf(sx1[2], sx1[3]));
        t0r = fmaxf(t0r, __shfl_xor(t0r, 16)); t0r = fmaxf(t0r, __shfl_xor(t0r, 32));
        t1r = fmaxf(t1r, __shfl_xor(t1r, 16)); t1r = fmaxf(t1r, __shfl_xor(t1r, 32));
        float ps0 = e00 + e01 + e02 + e03, ps1 = e10 + e11 + e12 + e13;
        ps0 += __shfl_xor(ps0, 16); ps0 += __shfl_xor(ps0, 32);
        ps1 += __shfl_xor(ps1, 16); ps1 += __shfl_xor(ps1, 32);
        // 5. stage V + PV (same-wave slab, DS in-order)
        #pragma unroll
        for (int i = 0; i < 4; ++i) {
            bf16x4 wlo = { vst[i][0], vst[i][1], vst[i][2], vst[i][3] };
            bf16x4 whi = { vst[i][4], vst[i][5], vst[i][6], vst[i][7] };
            *(bf16x4*)&Vslab[w][vwoff[i]]     = wlo;
            *(bf16x4*)&Vslab[w][vwoff[i] + 4] = whi;
        }
        #pragma unroll
        for (int i = 0; i < 2; ++i) {
            bf16x4 pf = i ? pf1 : pf0;
            #pragma unroll
            for (int dt = 0; dt < 4; ++dt) {
                bf16x4 afr = *(const bf16x4*)&Vslab[w][i * (64 * VS_PITCH) + (dt * 16 + l16) * VS_PITCH + qq * 4];
                acc[i][dt] = __builtin_amdgcn_mfma_f32_16x16x16bf16_1k(afr, pf, acc[i][dt], 0, 0, 0);
            }
        }
        // 6. V refill (vst dead after PV)
        vload(tb + t + 1, vst);
        // 7. rescale to new running max
        float mnew0 = fmaxf(mrun0, t0r), mnew1 = fmaxf(mrun1, t1r);
        float corr0 = __expf(mrun0 - mnew0), corr1 = __expf(mrun1 - mnew1);
        srun0 = (srun0 + ps0) * corr0; srun1 = (srun1 + ps1) * corr1;
        acc[0][0] *= corr0; acc[0][1] *= corr0; acc[0][2] *= corr0; acc[0][3] *= corr0;
        acc[1][0] *= corr1; acc[1][1] *= corr1; acc[1][2] *= corr1; acc[1][3] *= corr1;
        mrun0 = mnew0; mrun1 = mnew1;
        block_sync();   // B_end: Smix reads done; Sraw(t+1) published
    }

    if (pacc) {
        // partial epilogue: unnormalized acc + (m, s) per (g, l)
        #pragma unroll
        for (int i = 0; i < 2; ++i) {
            int g = 2 * w + i;
            #pragma unroll
            for (int dt = 0; dt < 4; ++dt)
                *(f32x4*)&pacc[(((size_t)n * 16 + g) * 16 + l16) * 64 + dt * 16 + qq * 4] = acc[i][dt];
        }
        if (qq == 0) {
            *(float2*)&pms[(((size_t)n * 16 + 2 * w)     * 16 + l16) * 2] = make_float2(mrun0, srun0);
            *(float2*)&pms[(((size_t)n * 16 + 2 * w + 1) * 16 + l16) * 2] = make_float2(mrun1, srun1);
        }
    } else {
        float inv0 = 1.f / srun0, inv1 = 1.f / srun1;
        #pragma unroll
        for (int i = 0; i < 2; ++i) {
            float inv = i ? inv1 : inv0;
            #pragma unroll
            for (int dt = 0; dt < 4; ++dt) {
                f32x4 a = acc[i][dt];
                bf16x4 ov = { f2bf(a[0] * inv), f2bf(a[1] * inv), f2bf(a[2] * inv), f2bf(a[3] * inv) };
                *(bf16x4*)(attn_out + ((size_t)(b * L_ + l0 + l16)) * D_ + (2 * w + i) * 64 + dt * 16 + qq * 4) = ov;
            }
        }
    }
}

// ---------------------------------------------------------------------------
// Kernel 2b: merge the 2 m-split partials -> bf16 attn.
// ---------------------------------------------------------------------------
__global__ __launch_bounds__(256) void merge_attn(
    const float* __restrict__ pacc, const float* __restrict__ pms,
    short* __restrict__ attn)
{
    const int cid = blockIdx.x * 256 + threadIdx.x;
    const int d4 = cid & 15;
    const int g  = (cid >> 4) & 15;
    const int l  = (cid >> 8) & (L_ - 1);
    const int b  = cid >> 19;
    const int lt = l >> 4, l16 = l & 15;
    const int n0 = ((lt >> 2) << 3) + (b << 2) + (lt & 3);
    const int n1 = n0 + 256;

    float2 ms0 = *(const float2*)&pms[(((size_t)n0 * 16 + g) * 16 + l16) * 2];
    float2 ms1 = *(const float2*)&pms[(((size_t)n1 * 16 + g) * 16 + l16) * 2];
    f32x4 o0 = *(const f32x4*)&pacc[(((size_t)n0 * 16 + g) * 16 + l16) * 64 + d4 * 4];
    f32x4 o1 = *(const f32x4*)&pacc[(((size_t)n1 * 16 + g) * 16 + l16) * 64 + d4 * 4];
    float Mx = fmaxf(ms0.x, ms1.x);
    float w0 = __expf(ms0.x - Mx), w1 = __expf(ms1.x - Mx);
    float s = ms0.y * w0 + ms1.y * w1;
    float inv = 1.f / s;
    f32x4 o = o0 * w0 + o1 * w1;
    bf16x4 ov = { f2bf(o[0] * inv), f2bf(o[1] * inv), f2bf(o[2] * inv), f2bf(o[3] * inv) };
    *(bf16x4*)(attn + ((size_t)(b * L_ + l) * D_) + g * 64 + d4 * 4) = ov;
}

// ---------------------------------------------------------------------------
// Kernel 3: output projection (attn bf16 @ Wo^T + bo) -> f32, MFMA.
// ---------------------------------------------------------------------------
__global__ __launch_bounds__(256) void out_mfma(
    const short* __restrict__ attn, const float* __restrict__ Wo,
    const float* __restrict__ bo, float* __restrict__ out)
{
    __shared__ short Ws[128][40];
    __shared__ short Xs[128][40];

    const int tid = threadIdx.x;
    const int w = tid >> 6, lane = tid & 63;
    const int l16 = lane & 15, qq = lane >> 4;
    const int m0 = blockIdx.x * 128;
    const int n0 = blockIdx.y * 128;
    const int ar0 = 64 * (w & 1);
    const int br0 = 64 * (w >> 1);

    f32x4 acc[4][4] = {};

    for (int k0 = 0; k0 < D_; k0 += 32) {
        #pragma unroll
        for (int i = 0; i < 4; ++i) {
            int fidx = i * 256 + tid;
            int r = fidx >> 3, c = fidx & 7;
            float4 wv4 = *(const float4*)(Wo + (size_t)(n0 + r) * D_ + k0 + c * 4);
            bf16x4 wb = { f2bf(wv4.x), f2bf(wv4.y), f2bf(wv4.z), f2bf(wv4.w) };
            *(bf16x4*)&Ws[r][c * 4] = wb;
        }
        #pragma unroll
        for (int i = 0; i < 2; ++i) {
            int cidx = i * 256 + tid;
            int r = cidx >> 2, c = cidx & 3;
            bf16x8 xv = *(const bf16x8*)(attn + (size_t)(m0 + r) * D_ + k0 + c * 8);
            *(bf16x8*)&Xs[r][c * 8] = xv;
        }
        __syncthreads();
        bf16x8 af[4], bfv[4];
        #pragma unroll
        for (int i = 0; i < 4; ++i) {
            af[i]  = *(const bf16x8*)&Ws[ar0 + 16 * i + l16][qq * 8];
            bfv[i] = *(const bf16x8*)&Xs[br0 + 16 * i + l16][qq * 8];
        }
        #pragma unroll
        for (int i = 0; i < 4; ++i)
            #pragma unroll
            for (int j = 0; j < 4; ++j)
                acc[i][j] = __builtin_amdgcn_mfma_f32_16x16x32_bf16(af[i], bfv[j], acc[i][j], 0, 0, 0);
        __syncthreads();
    }

    #pragma unroll
    for (int i = 0; i < 4; ++i) {
        int nb = n0 + ar0 + 16 * i + qq * 4;
        float4 b4 = *(const float4*)(bo + nb);
        #pragma unroll
        for (int j = 0; j < 4; ++j) {
            int m = m0 + br0 + 16 * j + l16;
            f32x4 c = acc[i][j];
            float4 ov = make_float4(c[0] + b4.x, c[1] + b4.y, c[2] + b4.z, c[3] + b4.w);
            *(float4*)&out[(size_t)m * D_ + nb] = ov;
        }
    }
}

// ---------------------------------------------------------------------------
extern "C" void kernel_launch(void* const* d_in, const int* in_sizes, int n_in,
                              void* d_out, int out_size, void* d_ws, size_t ws_size,
                              hipStream_t stream) {
    const float* q  = (const float*)d_in[0];
    const float* k  = (const float*)d_in[1];
    const float* v  = (const float*)d_in[2];
    const float* Wq = (const float*)d_in[3];
    const float* bq = (const float*)d_in[4];
    const float* Wk = (const float*)d_in[5];
    const float* bk = (const float*)d_in[6];
    const float* Wv = (const float*)d_in[7];
    const float* bv = (const float*)d_in[8];
    const float* Wo = (const float*)d_in[9];
    const float* bo = (const float*)d_in[10];
    const float* P  = (const float*)d_in[11];
    float* out = (float*)d_out;

    // ws: qh 8M | qlo 8M | kh 8M | vht 8M | attn 8M | pacc 32MiB | pms 1MiB
    char* ws = (char*)d_ws;
    short* qh   = (short*)(ws);
    short* qlo  = (short*)(ws + (size_t)8 * 1024 * 1024);
    short* kh   = (short*)(ws + (size_t)16 * 1024 * 1024);
    short* vht  = (short*)(ws + (size_t)24 * 1024 * 1024);
    short* attn = (short*)(ws + (size_t)32 * 1024 * 1024);
    float* pacc = (float*)(ws + (size_t)40 * 1024 * 1024);
    float* pms  = (float*)(ws + (size_t)40 * 1024 * 1024 + (size_t)512 * 16 * 16 * 64 * 4);
    const size_t need2 = (size_t)40 * 1024 * 1024
                       + (size_t)512 * 16 * 16 * 64 * 4    // pacc 32 MiB
                       + (size_t)512 * 16 * 16 * 2 * 4;    // pms 1 MiB
    const bool split2 = (ws_size >= need2);

    proj_mfma<<<dim3(M_ / 128, D_ / 128, 3), 256, 0, stream>>>(
        q, k, v, Wq, bq, Wk, bk, Wv, bv, qh, qlo, kh, vht);
    if (split2) {
        attn_mfma<<<dim3(512), 512, 0, stream>>>(qh, qlo, kh, vht, P, attn, pacc, pms, 64);
        merge_attn<<<dim3(4096), 256, 0, stream>>>(pacc, pms, attn);
    } else {
        attn_mfma<<<dim3(256), 512, 0, stream>>>(qh, qlo, kh, vht, P, attn, nullptr, nullptr, 128);
    }
    out_mfma<<<dim3(M_ / 128, D_ / 128), 256, 0, stream>>>(attn, Wo, bo, out);
}

// Round 15
// 383.711 us; speedup vs baseline: 1.2397x; 1.0103x over previous
//
#include <hip/hip_runtime.h>

#define D_  1024
#define H_  16
#define HD_ 64
#define L_  2048
#define B_  2
#define M_  (B_*L_)   // 4096 rows

typedef float f32x4  __attribute__((ext_vector_type(4)));
typedef short bf16x4 __attribute__((ext_vector_type(4)));
typedef short bf16x8 __attribute__((ext_vector_type(8)));

#define SRAW_PITCH 18   // f32 per l-row (72B): conflict-free b64/scalar patterns
#define SRAW_SLAB  (16 * SRAW_PITCH)   // 288 f32 per h (or m) slab
#define VS_PITCH   20   // shorts per d-row (40B): 16 data + 4 pad, b64-aligned

__device__ __forceinline__ float bf2f(short s) {
    return __uint_as_float(((unsigned int)(unsigned short)s) << 16);
}
__device__ __forceinline__ short f2bf(float f) {   // RNE
    unsigned u = __float_as_uint(f);
    unsigned r = (u + 0x7FFFu + ((u >> 16) & 1u)) >> 16;
    return (short)r;
}
// Raw barrier: orders LDS (lgkmcnt(0) + "memory" clobber), does NOT drain vmcnt.
__device__ __forceinline__ void block_sync() {
    asm volatile("s_waitcnt lgkmcnt(0)" ::: "memory");
    __builtin_amdgcn_sched_barrier(0);
    __builtin_amdgcn_s_barrier();
    __builtin_amdgcn_sched_barrier(0);
}

// ---------------------------------------------------------------------------
// Kernel 1: QKV projections via bf16 MFMA. 128x128 tile, K-step 32, 256 thr.
// z=0: q -> qh(hi)+qlo  [b][h][l][64]        (A=W rows n, B=X cols m: D[n][m])
// z=1: k -> kh          [b][h][l][64]        (same)
// z=2: v -> vht         [b][h][64][L]        (A=X rows m, B=W cols n: D[m][n])
// ---------------------------------------------------------------------------
__global__ __launch_bounds__(256) void proj_mfma(
    const float* __restrict__ q, const float* __restrict__ k, const float* __restrict__ v,
    const float* __restrict__ Wq, const float* __restrict__ bq,
    const float* __restrict__ Wk, const float* __restrict__ bk,
    const float* __restrict__ Wv, const float* __restrict__ bv,
    short* __restrict__ qh, short* __restrict__ qlo,
    short* __restrict__ kh, short* __restrict__ vht)
{
    const int z = blockIdx.z;
    const float* X    = (z == 0) ? q  : (z == 1) ? k  : v;
    const float* W    = (z == 0) ? Wq : (z == 1) ? Wk : Wv;
    const float* bias = (z == 0) ? bq : (z == 1) ? bk : bv;

    __shared__ short Ws[128][40];
    __shared__ short Xs[128][40];

    const int tid  = threadIdx.x;
    const int w    = tid >> 6, lane = tid & 63;
    const int l16  = lane & 15, qq = lane >> 4;
    const int m0   = blockIdx.x * 128;
    const int n0   = blockIdx.y * 128;
    const int ar0  = 64 * (w & 1);
    const int br0  = 64 * (w >> 1);

    f32x4 acc[4][4] = {};

    for (int k0 = 0; k0 < D_; k0 += 32) {
        #pragma unroll
        for (int i = 0; i < 4; ++i) {
            int fidx = i * 256 + tid;
            int r = fidx >> 3, c = fidx & 7;
            float4 wv4 = *(const float4*)(W + (size_t)(n0 + r) * D_ + k0 + c * 4);
            float4 xv4 = *(const float4*)(X + (size_t)(m0 + r) * D_ + k0 + c * 4);
            bf16x4 wb = { f2bf(wv4.x), f2bf(wv4.y), f2bf(wv4.z), f2bf(wv4.w) };
            bf16x4 xb = { f2bf(xv4.x), f2bf(xv4.y), f2bf(xv4.z), f2bf(xv4.w) };
            *(bf16x4*)&Ws[r][c * 4] = wb;
            *(bf16x4*)&Xs[r][c * 4] = xb;
        }
        __syncthreads();
        bf16x8 af[4], bfv[4];
        #pragma unroll
        for (int i = 0; i < 4; ++i) {
            const short* Ab = (z < 2) ? &Ws[ar0 + 16 * i + l16][qq * 8]
                                      : &Xs[ar0 + 16 * i + l16][qq * 8];
            const short* Bb = (z < 2) ? &Xs[br0 + 16 * i + l16][qq * 8]
                                      : &Ws[br0 + 16 * i + l16][qq * 8];
            af[i]  = *(const bf16x8*)Ab;
            bfv[i] = *(const bf16x8*)Bb;
        }
        #pragma unroll
        for (int i = 0; i < 4; ++i)
            #pragma unroll
            for (int j = 0; j < 4; ++j)
                acc[i][j] = __builtin_amdgcn_mfma_f32_16x16x32_bf16(af[i], bfv[j], acc[i][j], 0, 0, 0);
        __syncthreads();
    }

    if (z < 2) {
        #pragma unroll
        for (int i = 0; i < 4; ++i) {
            int nb = n0 + ar0 + 16 * i + qq * 4;
            float4 b4 = *(const float4*)(bias + nb);
            int h = nb >> 6, hd = nb & 63;
            #pragma unroll
            for (int j = 0; j < 4; ++j) {
                int m = m0 + br0 + 16 * j + l16;
                int bb = m >> 11, l = m & (L_ - 1);
                size_t o = ((((size_t)bb * H_ + h) * L_) + l) * HD_ + hd;
                f32x4 c = acc[i][j];
                float v0 = c[0] + b4.x, v1 = c[1] + b4.y, v2 = c[2] + b4.z, v3 = c[3] + b4.w;
                bf16x4 hi = { f2bf(v0), f2bf(v1), f2bf(v2), f2bf(v3) };
                if (z == 0) {
                    *(bf16x4*)&qh[o] = hi;
                    bf16x4 lo = { f2bf(v0 - bf2f(hi[0])), f2bf(v1 - bf2f(hi[1])),
                                  f2bf(v2 - bf2f(hi[2])), f2bf(v3 - bf2f(hi[3])) };
                    *(bf16x4*)&qlo[o] = lo;
                } else {
                    *(bf16x4*)&kh[o] = hi;
                }
            }
        }
    } else {
        // D[m][n]: rows m = m0+ar0+16i+4qq+r ; cols n = n0+br0+16j+l16
        #pragma unroll
        for (int i = 0; i < 4; ++i) {
            int mb = m0 + ar0 + 16 * i + qq * 4;
            int bb = mb >> 11, lb = mb & (L_ - 1);
            #pragma unroll
            for (int j = 0; j < 4; ++j) {
                int n = n0 + br0 + 16 * j + l16;
                int h = n >> 6, hd = n & 63;
                float bn = bias[n];
                size_t o = (((size_t)bb * H_ + h) * HD_ + hd) * (size_t)L_ + lb;
                f32x4 c = acc[i][j];
                bf16x4 ov = { f2bf(c[0] + bn), f2bf(c[1] + bn), f2bf(c[2] + bn), f2bf(c[3] + bn) };
                *(bf16x4*)&vht[o] = ov;
            }
        }
    }
}

// ---------------------------------------------------------------------------
// Kernel 2: fused talking-heads attention, m-SPLIT (flash split-K).
// Grid = 256 * 2; block n: half = n>>8, covers ntiles m-tiles. 512 thr.
// R15: Smix/Vslab LDS UNION (disjoint lifetimes, 3rd barrier between Smix
// reads and V staging) -> 60416 B/block -> TRUE 2 blocks/CU co-residency.
// Hazards: Smix-wr(t) <B_mid< Smix-rd(t) <B_pv< Vslab-wr/rd(t) <B_end<
// Smix-wr(t+1); Sraw mix-rd(t) <B_mid< qkt-wr(t+1) <B_end< mix-rd(t+1).
// ---------------------------------------------------------------------------
__global__ __launch_bounds__(512, 2) void attn_mfma(
    const short* __restrict__ qh, const short* __restrict__ qlo,
    const short* __restrict__ kh, const short* __restrict__ vht,
    const float* __restrict__ P, short* __restrict__ attn_out,
    float* __restrict__ pacc, float* __restrict__ pms, int ntiles)
{
    __shared__ __align__(16) float Sraw[16 * SRAW_SLAB];   // [h][l][18] 18432 B
    __shared__ __align__(16) char  UPool[8 * 2 * 64 * VS_PITCH * 2];  // 40960 B union
    __shared__ float PmS[256];                             // 1024 B  (total 60416)

    float* Smix  = (float*)UPool;                          // [m][l][18] f32 (18432 B)
    const int tid  = threadIdx.x;
    const int n    = blockIdx.x;
    const int half = n >> 8;
    const int inr  = n & 255;
    const int b    = (inr >> 2) & 1;                       // XCD swizzle
    const int l0   = ((inr >> 3) * 4 + (inr & 3)) * 16;
    const int tb   = half * ntiles;                        // first m-tile
    const int w    = tid >> 6, lane = tid & 63;
    const int l16  = lane & 15, qq = lane >> 4;
    const size_t hb = (size_t)b * H_;
    short* VslabW = (short*)UPool + w * (2 * 64 * VS_PITCH);  // per-wave 5120 B

    // ---- Q frags (persistent)
    bf16x8 qf[2][2][2];
    #pragma unroll
    for (int hh = 0; hh < 2; ++hh)
        #pragma unroll
        for (int kc = 0; kc < 2; ++kc) {
            size_t off = ((hb + 2 * w + hh) * L_ + l0 + l16) * HD_ + kc * 32 + qq * 8;
            qf[hh][kc][0] = *(const bf16x8*)(qh  + off);
            qf[hh][kc][1] = *(const bf16x8*)(qlo + off);
        }

    // V^T staging mapping
    int vgi_[4], vd_[4];
    const int vc = lane & 1;
    #pragma unroll
    for (int i = 0; i < 4; ++i) {
        int vrow = i * 32 + (lane >> 1);
        vgi_[i] = vrow >> 6;
        vd_[i]  = vrow & 63;
    }
    int vwoff[4];
    #pragma unroll
    for (int i = 0; i < 4; ++i)
        vwoff[i] = vgi_[i] * (64 * VS_PITCH) + vd_[i] * VS_PITCH + vc * 8;

    auto kload = [&](int tile, bf16x8 (&kdst)[2][2]) {
        const int mn = (tile & 127) * 16;
        #pragma unroll
        for (int hh = 0; hh < 2; ++hh)
            #pragma unroll
            for (int kc = 0; kc < 2; ++kc)
                kdst[hh][kc] = *(const bf16x8*)(kh + ((hb + 2 * w + hh) * L_ + mn + l16) * HD_ + kc * 32 + qq * 8);
    };
    auto vload = [&](int tile, bf16x8 (&vdst)[4]) {
        const int mn = (tile & 127) * 16;
        #pragma unroll
        for (int i = 0; i < 4; ++i)
            vdst[i] = *(const bf16x8*)(vht + ((hb + 2 * w + vgi_[i]) * HD_ + vd_[i]) * (size_t)L_ + mn + vc * 8);
    };

    bf16x8 kP[2][2], vst[4];
    kload(tb, kP); vload(tb, vst);

    if (tid < 256) PmS[tid] = P[tid] * 0.125f;            // fold 1/sqrt(64)

    f32x4 acc[2][4];
    #pragma unroll
    for (int dt = 0; dt < 4; ++dt) { acc[0][dt] = (f32x4){0.f,0.f,0.f,0.f}; acc[1][dt] = (f32x4){0.f,0.f,0.f,0.f}; }
    float mrun0 = 0.f, mrun1 = 0.f, srun0 = 0.f, srun1 = 0.f;   // deferred-max

    // QK^T: D[m][l], col=l16, rows m=qq*4+j.
    auto qkt = [&](bf16x8 (&kr)[2][2], float* sb) {
        #pragma unroll
        for (int hh = 0; hh < 2; ++hh) {
            f32x4 s = (f32x4){0.f,0.f,0.f,0.f};
            s = __builtin_amdgcn_mfma_f32_16x16x32_bf16(kr[hh][0], qf[hh][0][0], s, 0, 0, 0);
            s = __builtin_amdgcn_mfma_f32_16x16x32_bf16(kr[hh][0], qf[hh][0][1], s, 0, 0, 0);
            s = __builtin_amdgcn_mfma_f32_16x16x32_bf16(kr[hh][1], qf[hh][1][0], s, 0, 0, 0);
            s = __builtin_amdgcn_mfma_f32_16x16x32_bf16(kr[hh][1], qf[hh][1][1], s, 0, 0, 0);
            float* sp = sb + ((2 * w + hh) * 16 + l16) * SRAW_PITCH + qq * 4;
            *(float2*)sp       = make_float2(s[0], s[1]);
            *(float2*)(sp + 2) = make_float2(s[2], s[3]);
        }
    };

    // prologue: QK^T(tile tb) -> Sraw, publish (also PmS)
    qkt(kP, Sraw);
    block_sync();
    kload(tb + 1, kP);

    bf16x4 PAhi, PAlo;
    {
        float p0 = PmS[(qq * 4 + 0) * 16 + l16];
        float p1 = PmS[(qq * 4 + 1) * 16 + l16];
        float p2 = PmS[(qq * 4 + 2) * 16 + l16];
        float p3 = PmS[(qq * 4 + 3) * 16 + l16];
        PAhi = (bf16x4){ f2bf(p0), f2bf(p1), f2bf(p2), f2bf(p3) };
        PAlo = (bf16x4){ f2bf(p0 - bf2f(PAhi[0])), f2bf(p1 - bf2f(PAhi[1])),
                         f2bf(p2 - bf2f(PAhi[2])), f2bf(p3 - bf2f(PAhi[3])) };
    }

    for (int t = 0; t < ntiles; ++t) {
        // 1. mix via MFMA: B = scalar-gathered S hi/lo -> Smix[m][l][g]
        #pragma unroll
        for (int mi = 0; mi < 2; ++mi) {
            const int m = 2 * w + mi;
            float sv0 = Sraw[(qq * 4 + 0) * SRAW_SLAB + l16 * SRAW_PITCH + m];
            float sv1 = Sraw[(qq * 4 + 1) * SRAW_SLAB + l16 * SRAW_PITCH + m];
            float sv2 = Sraw[(qq * 4 + 2) * SRAW_SLAB + l16 * SRAW_PITCH + m];
            float sv3 = Sraw[(qq * 4 + 3) * SRAW_SLAB + l16 * SRAW_PITCH + m];
            bf16x4 bhi = { f2bf(sv0), f2bf(sv1), f2bf(sv2), f2bf(sv3) };
            bf16x4 blo = { f2bf(sv0 - bf2f(bhi[0])), f2bf(sv1 - bf2f(bhi[1])),
                           f2bf(sv2 - bf2f(bhi[2])), f2bf(sv3 - bf2f(bhi[3])) };
            f32x4 c = (f32x4){0.f, 0.f, 0.f, 0.f};
            c = __builtin_amdgcn_mfma_f32_16x16x16bf16_1k(PAhi, bhi, c, 0, 0, 0);
            c = __builtin_amdgcn_mfma_f32_16x16x16bf16_1k(PAhi, blo, c, 0, 0, 0);
            c = __builtin_amdgcn_mfma_f32_16x16x16bf16_1k(PAlo, bhi, c, 0, 0, 0);
            float* sp = Smix + m * SRAW_SLAB + l16 * SRAW_PITCH + qq * 4;
            *(float2*)sp       = make_float2(c[0], c[1]);
            *(float2*)(sp + 2) = make_float2(c[2], c[3]);
        }
        block_sync();   // B_mid: Smix visible; mix-reads of Sraw done
        // 2. QK^T(tile tb+t+1) -> Sraw (safe: all mix-reads complete)
        qkt(kP, Sraw);
        kload(tb + t + 2, kP);
        // 3. softmax inputs from Smix
        float sx0[4], sx1[4];
        #pragma unroll
        for (int j = 0; j < 4; ++j) {
            const float* mp = Smix + (qq * 4 + j) * SRAW_SLAB + l16 * SRAW_PITCH;
            sx0[j] = mp[2 * w];
            sx1[j] = mp[2 * w + 1];
        }
        // 4. deferred-max exps
        float e00 = __expf(sx0[0] - mrun0), e01 = __expf(sx0[1] - mrun0);
        float e02 = __expf(sx0[2] - mrun0), e03 = __expf(sx0[3] - mrun0);
        float e10 = __expf(sx1[0] - mrun1), e11 = __expf(sx1[1] - mrun1);
        float e12 = __expf(sx1[2] - mrun1), e13 = __expf(sx1[3] - mrun1);
        bf16x4 pf0 = { f2bf(e00), f2bf(e01), f2bf(e02), f2bf(e03) };
        bf16x4 pf1 = { f2bf(e10), f2bf(e11), f2bf(e12), f2bf(e13) };
        float t0r = fmaxf(fmaxf(sx0[0], sx0[1]), fmaxf(sx0[2], sx0[3]));
        float t1r = fmaxf(fmaxf(sx1[0], sx1[1]), fmaxf(sx1[2], sx1[3]));
        t0r = fmaxf(t0r, __shfl_xor(t0r, 16)); t0r = fmaxf(t0r, __shfl_xor(t0r, 32));
        t1r = fmaxf(t1r, __shfl_xor(t1r, 16)); t1r = fmaxf(t1r, __shfl_xor(t1r, 32));
        float ps0 = e00 + e01 + e02 + e03, ps1 = e10 + e11 + e12 + e13;
        ps0 += __shfl_xor(ps0, 16); ps0 += __shfl_xor(ps0, 32);
        ps1 += __shfl_xor(ps1, 16); ps1 += __shfl_xor(ps1, 32);
        block_sync();   // B_pv: ALL waves' Smix reads done -> union space free for V
        // 5. stage V + PV (same-wave slab in union space, DS in-order)
        #pragma unroll
        for (int i = 0; i < 4; ++i) {
            bf16x4 wlo = { vst[i][0], vst[i][1], vst[i][2], vst[i][3] };
            bf16x4 whi = { vst[i][4], vst[i][5], vst[i][6], vst[i][7] };
            *(bf16x4*)&VslabW[vwoff[i]]     = wlo;
            *(bf16x4*)&VslabW[vwoff[i] + 4] = whi;
        }
        #pragma unroll
        for (int i = 0; i < 2; ++i) {
            bf16x4 pf = i ? pf1 : pf0;
            #pragma unroll
            for (int dt = 0; dt < 4; ++dt) {
                bf16x4 afr = *(const bf16x4*)&VslabW[i * (64 * VS_PITCH) + (dt * 16 + l16) * VS_PITCH + qq * 4];
                acc[i][dt] = __builtin_amdgcn_mfma_f32_16x16x16bf16_1k(afr, pf, acc[i][dt], 0, 0, 0);
            }
        }
        // 6. V refill (vst dead after PV)
        vload(tb + t + 1, vst);
        // 7. rescale to new running max
        float mnew0 = fmaxf(mrun0, t0r), mnew1 = fmaxf(mrun1, t1r);
        float corr0 = __expf(mrun0 - mnew0), corr1 = __expf(mrun1 - mnew1);
        srun0 = (srun0 + ps0) * corr0; srun1 = (srun1 + ps1) * corr1;
        acc[0][0] *= corr0; acc[0][1] *= corr0; acc[0][2] *= corr0; acc[0][3] *= corr0;
        acc[1][0] *= corr1; acc[1][1] *= corr1; acc[1][2] *= corr1; acc[1][3] *= corr1;
        mrun0 = mnew0; mrun1 = mnew1;
        block_sync();   // B_end: Vslab reads done -> next mix may write Smix
    }

    if (pacc) {
        // partial epilogue: unnormalized acc + (m, s) per (g, l)
        #pragma unroll
        for (int i = 0; i < 2; ++i) {
            int g = 2 * w + i;
            #pragma unroll
            for (int dt = 0; dt < 4; ++dt)
                *(f32x4*)&pacc[(((size_t)n * 16 + g) * 16 + l16) * 64 + dt * 16 + qq * 4] = acc[i][dt];
        }
        if (qq == 0) {
            *(float2*)&pms[(((size_t)n * 16 + 2 * w)     * 16 + l16) * 2] = make_float2(mrun0, srun0);
            *(float2*)&pms[(((size_t)n * 16 + 2 * w + 1) * 16 + l16) * 2] = make_float2(mrun1, srun1);
        }
    } else {
        float inv0 = 1.f / srun0, inv1 = 1.f / srun1;
        #pragma unroll
        for (int i = 0; i < 2; ++i) {
            float inv = i ? inv1 : inv0;
            #pragma unroll
            for (int dt = 0; dt < 4; ++dt) {
                f32x4 a = acc[i][dt];
                bf16x4 ov = { f2bf(a[0] * inv), f2bf(a[1] * inv), f2bf(a[2] * inv), f2bf(a[3] * inv) };
                *(bf16x4*)(attn_out + ((size_t)(b * L_ + l0 + l16)) * D_ + (2 * w + i) * 64 + dt * 16 + qq * 4) = ov;
            }
        }
    }
}

// ---------------------------------------------------------------------------
// Kernel 2b: merge the 2 m-split partials -> bf16 attn.
// ---------------------------------------------------------------------------
__global__ __launch_bounds__(256) void merge_attn(
    const float* __restrict__ pacc, const float* __restrict__ pms,
    short* __restrict__ attn)
{
    const int cid = blockIdx.x * 256 + threadIdx.x;
    const int d4 = cid & 15;
    const int g  = (cid >> 4) & 15;
    const int l  = (cid >> 8) & (L_ - 1);
    const int b  = cid >> 19;
    const int lt = l >> 4, l16 = l & 15;
    const int n0 = ((lt >> 2) << 3) + (b << 2) + (lt & 3);
    const int n1 = n0 + 256;

    float2 ms0 = *(const float2*)&pms[(((size_t)n0 * 16 + g) * 16 + l16) * 2];
    float2 ms1 = *(const float2*)&pms[(((size_t)n1 * 16 + g) * 16 + l16) * 2];
    f32x4 o0 = *(const f32x4*)&pacc[(((size_t)n0 * 16 + g) * 16 + l16) * 64 + d4 * 4];
    f32x4 o1 = *(const f32x4*)&pacc[(((size_t)n1 * 16 + g) * 16 + l16) * 64 + d4 * 4];
    float Mx = fmaxf(ms0.x, ms1.x);
    float w0 = __expf(ms0.x - Mx), w1 = __expf(ms1.x - Mx);
    float s = ms0.y * w0 + ms1.y * w1;
    float inv = 1.f / s;
    f32x4 o = o0 * w0 + o1 * w1;
    bf16x4 ov = { f2bf(o[0] * inv), f2bf(o[1] * inv), f2bf(o[2] * inv), f2bf(o[3] * inv) };
    *(bf16x4*)(attn + ((size_t)(b * L_ + l) * D_) + g * 64 + d4 * 4) = ov;
}

// ---------------------------------------------------------------------------
// Kernel 3: output projection (attn bf16 @ Wo^T + bo) -> f32, MFMA.
// ---------------------------------------------------------------------------
__global__ __launch_bounds__(256) void out_mfma(
    const short* __restrict__ attn, const float* __restrict__ Wo,
    const float* __restrict__ bo, float* __restrict__ out)
{
    __shared__ short Ws[128][40];
    __shared__ short Xs[128][40];

    const int tid = threadIdx.x;
    const int w = tid >> 6, lane = tid & 63;
    const int l16 = lane & 15, qq = lane >> 4;
    const int m0 = blockIdx.x * 128;
    const int n0 = blockIdx.y * 128;
    const int ar0 = 64 * (w & 1);
    const int br0 = 64 * (w >> 1);

    f32x4 acc[4][4] = {};

    for (int k0 = 0; k0 < D_; k0 += 32) {
        #pragma unroll
        for (int i = 0; i < 4; ++i) {
            int fidx = i * 256 + tid;
            int r = fidx >> 3, c = fidx & 7;
            float4 wv4 = *(const float4*)(Wo + (size_t)(n0 + r) * D_ + k0 + c * 4);
            bf16x4 wb = { f2bf(wv4.x), f2bf(wv4.y), f2bf(wv4.z), f2bf(wv4.w) };
            *(bf16x4*)&Ws[r][c * 4] = wb;
        }
        #pragma unroll
        for (int i = 0; i < 2; ++i) {
            int cidx = i * 256 + tid;
            int r = cidx >> 2, c = cidx & 3;
            bf16x8 xv = *(const bf16x8*)(attn + (size_t)(m0 + r) * D_ + k0 + c * 8);
            *(bf16x8*)&Xs[r][c * 8] = xv;
        }
        __syncthreads();
        bf16x8 af[4], bfv[4];
        #pragma unroll
        for (int i = 0; i < 4; ++i) {
            af[i]  = *(const bf16x8*)&Ws[ar0 + 16 * i + l16][qq * 8];
            bfv[i] = *(const bf16x8*)&Xs[br0 + 16 * i + l16][qq * 8];
        }
        #pragma unroll
        for (int i = 0; i < 4; ++i)
            #pragma unroll
            for (int j = 0; j < 4; ++j)
                acc[i][j] = __builtin_amdgcn_mfma_f32_16x16x32_bf16(af[i], bfv[j], acc[i][j], 0, 0, 0);
        __syncthreads();
    }

    #pragma unroll
    for (int i = 0; i < 4; ++i) {
        int nb = n0 + ar0 + 16 * i + qq * 4;
        float4 b4 = *(const float4*)(bo + nb);
        #pragma unroll
        for (int j = 0; j < 4; ++j) {
            int m = m0 + br0 + 16 * j + l16;
            f32x4 c = acc[i][j];
            float4 ov = make_float4(c[0] + b4.x, c[1] + b4.y, c[2] + b4.z, c[3] + b4.w);
            *(float4*)&out[(size_t)m * D_ + nb] = ov;
        }
    }
}

// ---------------------------------------------------------------------------
extern "C" void kernel_launch(void* const* d_in, const int* in_sizes, int n_in,
                              void* d_out, int out_size, void* d_ws, size_t ws_size,
                              hipStream_t stream) {
    const float* q  = (const float*)d_in[0];
    const float* k  = (const float*)d_in[1];
    const float* v  = (const float*)d_in[2];
    const float* Wq = (const float*)d_in[3];
    const float* bq = (const float*)d_in[4];
    const float* Wk = (const float*)d_in[5];
    const float* bk = (const float*)d_in[6];
    const float* Wv = (const float*)d_in[7];
    const float* bv = (const float*)d_in[8];
    const float* Wo = (const float*)d_in[9];
    const float* bo = (const float*)d_in[10];
    const float* P  = (const float*)d_in[11];
    float* out = (float*)d_out;

    // ws: qh 8M | qlo 8M | kh 8M | vht 8M | attn 8M | pacc 32MiB | pms 1MiB
    char* ws = (char*)d_ws;
    short* qh   = (short*)(ws);
    short* qlo  = (short*)(ws + (size_t)8 * 1024 * 1024);
    short* kh   = (short*)(ws + (size_t)16 * 1024 * 1024);
    short* vht  = (short*)(ws + (size_t)24 * 1024 * 1024);
    short* attn = (short*)(ws + (size_t)32 * 1024 * 1024);
    float* pacc = (float*)(ws + (size_t)40 * 1024 * 1024);
    float* pms  = (float*)(ws + (size_t)40 * 1024 * 1024 + (size_t)512 * 16 * 16 * 64 * 4);
    const size_t need2 = (size_t)40 * 1024 * 1024
                       + (size_t)512 * 16 * 16 * 64 * 4    // pacc 32 MiB
                       + (size_t)512 * 16 * 16 * 2 * 4;    // pms 1 MiB
    const bool split2 = (ws_size >= need2);

    proj_mfma<<<dim3(M_ / 128, D_ / 128, 3), 256, 0, stream>>>(
        q, k, v, Wq, bq, Wk, bk, Wv, bv, qh, qlo, kh, vht);
    if (split2) {
        attn_mfma<<<dim3(512), 512, 0, stream>>>(qh, qlo, kh, vht, P, attn, pacc, pms, 64);
        merge_attn<<<dim3(4096), 256, 0, stream>>>(pacc, pms, attn);
    } else {
        attn_mfma<<<dim3(256), 512, 0, stream>>>(qh, qlo, kh, vht, P, attn, nullptr, nullptr, 128);
    }
    out_mfma<<<dim3(M_ / 128, D_ / 128), 256, 0, stream>>>(attn, Wo, bo, out);
}

// Round 16
// 377.234 us; speedup vs baseline: 1.2609x; 1.0172x over previous
//
#include <hip/hip_runtime.h>

#define D_  1024
#define H_  16
#define HD_ 64
#define L_  2048
#define B_  2
#define M_  (B_*L_)   // 4096 rows

typedef float f32x4  __attribute__((ext_vector_type(4)));
typedef short bf16x4 __attribute__((ext_vector_type(4)));
typedef short bf16x8 __attribute__((ext_vector_type(8)));

#define SRAW_PITCH 20   // f32 per l-row (80B, 16B-aligned -> b128 writes)
#define SRAW_SLAB  (16 * SRAW_PITCH)   // 320 f32 per h (or m) slab
#define VS_PITCH   24   // shorts per d-row (48B, 16B-aligned -> b128 stage)

__device__ __forceinline__ float bf2f(short s) {
    return __uint_as_float(((unsigned int)(unsigned short)s) << 16);
}
__device__ __forceinline__ short f2bf(float f) {   // RNE
    unsigned u = __float_as_uint(f);
    unsigned r = (u + 0x7FFFu + ((u >> 16) & 1u)) >> 16;
    return (short)r;
}
// Raw barrier: orders LDS (lgkmcnt(0) + "memory" clobber), does NOT drain vmcnt.
__device__ __forceinline__ void block_sync() {
    asm volatile("s_waitcnt lgkmcnt(0)" ::: "memory");
    __builtin_amdgcn_sched_barrier(0);
    __builtin_amdgcn_s_barrier();
    __builtin_amdgcn_sched_barrier(0);
}

// ---------------------------------------------------------------------------
// Kernel 1: QKV projections via bf16 MFMA. 128x128 tile, K-step 32, 256 thr.
// z=0: q -> qh(hi)+qlo  [b][h][l][64]        (A=W rows n, B=X cols m: D[n][m])
// z=1: k -> kh          [b][h][l][64]        (same)
// z=2: v -> vht         [b][h][64][L]        (A=X rows m, B=W cols n: D[m][n])
// ---------------------------------------------------------------------------
__global__ __launch_bounds__(256) void proj_mfma(
    const float* __restrict__ q, const float* __restrict__ k, const float* __restrict__ v,
    const float* __restrict__ Wq, const float* __restrict__ bq,
    const float* __restrict__ Wk, const float* __restrict__ bk,
    const float* __restrict__ Wv, const float* __restrict__ bv,
    short* __restrict__ qh, short* __restrict__ qlo,
    short* __restrict__ kh, short* __restrict__ vht)
{
    const int z = blockIdx.z;
    const float* X    = (z == 0) ? q  : (z == 1) ? k  : v;
    const float* W    = (z == 0) ? Wq : (z == 1) ? Wk : Wv;
    const float* bias = (z == 0) ? bq : (z == 1) ? bk : bv;

    __shared__ short Ws[128][40];
    __shared__ short Xs[128][40];

    const int tid  = threadIdx.x;
    const int w    = tid >> 6, lane = tid & 63;
    const int l16  = lane & 15, qq = lane >> 4;
    const int m0   = blockIdx.x * 128;
    const int n0   = blockIdx.y * 128;
    const int ar0  = 64 * (w & 1);
    const int br0  = 64 * (w >> 1);

    f32x4 acc[4][4] = {};

    for (int k0 = 0; k0 < D_; k0 += 32) {
        #pragma unroll
        for (int i = 0; i < 4; ++i) {
            int fidx = i * 256 + tid;
            int r = fidx >> 3, c = fidx & 7;
            float4 wv4 = *(const float4*)(W + (size_t)(n0 + r) * D_ + k0 + c * 4);
            float4 xv4 = *(const float4*)(X + (size_t)(m0 + r) * D_ + k0 + c * 4);
            bf16x4 wb = { f2bf(wv4.x), f2bf(wv4.y), f2bf(wv4.z), f2bf(wv4.w) };
            bf16x4 xb = { f2bf(xv4.x), f2bf(xv4.y), f2bf(xv4.z), f2bf(xv4.w) };
            *(bf16x4*)&Ws[r][c * 4] = wb;
            *(bf16x4*)&Xs[r][c * 4] = xb;
        }
        __syncthreads();
        bf16x8 af[4], bfv[4];
        #pragma unroll
        for (int i = 0; i < 4; ++i) {
            const short* Ab = (z < 2) ? &Ws[ar0 + 16 * i + l16][qq * 8]
                                      : &Xs[ar0 + 16 * i + l16][qq * 8];
            const short* Bb = (z < 2) ? &Xs[br0 + 16 * i + l16][qq * 8]
                                      : &Ws[br0 + 16 * i + l16][qq * 8];
            af[i]  = *(const bf16x8*)Ab;
            bfv[i] = *(const bf16x8*)Bb;
        }
        #pragma unroll
        for (int i = 0; i < 4; ++i)
            #pragma unroll
            for (int j = 0; j < 4; ++j)
                acc[i][j] = __builtin_amdgcn_mfma_f32_16x16x32_bf16(af[i], bfv[j], acc[i][j], 0, 0, 0);
        __syncthreads();
    }

    if (z < 2) {
        #pragma unroll
        for (int i = 0; i < 4; ++i) {
            int nb = n0 + ar0 + 16 * i + qq * 4;
            float4 b4 = *(const float4*)(bias + nb);
            int h = nb >> 6, hd = nb & 63;
            #pragma unroll
            for (int j = 0; j < 4; ++j) {
                int m = m0 + br0 + 16 * j + l16;
                int bb = m >> 11, l = m & (L_ - 1);
                size_t o = ((((size_t)bb * H_ + h) * L_) + l) * HD_ + hd;
                f32x4 c = acc[i][j];
                float v0 = c[0] + b4.x, v1 = c[1] + b4.y, v2 = c[2] + b4.z, v3 = c[3] + b4.w;
                bf16x4 hi = { f2bf(v0), f2bf(v1), f2bf(v2), f2bf(v3) };
                if (z == 0) {
                    *(bf16x4*)&qh[o] = hi;
                    bf16x4 lo = { f2bf(v0 - bf2f(hi[0])), f2bf(v1 - bf2f(hi[1])),
                                  f2bf(v2 - bf2f(hi[2])), f2bf(v3 - bf2f(hi[3])) };
                    *(bf16x4*)&qlo[o] = lo;
                } else {
                    *(bf16x4*)&kh[o] = hi;
                }
            }
        }
    } else {
        // D[m][n]: rows m = m0+ar0+16i+4qq+r ; cols n = n0+br0+16j+l16
        #pragma unroll
        for (int i = 0; i < 4; ++i) {
            int mb = m0 + ar0 + 16 * i + qq * 4;
            int bb = mb >> 11, lb = mb & (L_ - 1);
            #pragma unroll
            for (int j = 0; j < 4; ++j) {
                int n = n0 + br0 + 16 * j + l16;
                int h = n >> 6, hd = n & 63;
                float bn = bias[n];
                size_t o = (((size_t)bb * H_ + h) * HD_ + hd) * (size_t)L_ + lb;
                f32x4 c = acc[i][j];
                bf16x4 ov = { f2bf(c[0] + bn), f2bf(c[1] + bn), f2bf(c[2] + bn), f2bf(c[3] + bn) };
                *(bf16x4*)&vht[o] = ov;
            }
        }
    }
}

// ---------------------------------------------------------------------------
// Kernel 2: fused talking-heads attention, m-SPLIT (flash split-K).
// R16: DS width consolidation -- qkt/Smix writes b128 (pitch 20), mix gather
// + softmax reads paired b64 (adjacent m / adjacent g), V staging b128
// (pitch 24). 40 -> 24 DS instr/wave/body. Union LDS kept: 70656 B.
// ---------------------------------------------------------------------------
__global__ __launch_bounds__(512, 2) void attn_mfma(
    const short* __restrict__ qh, const short* __restrict__ qlo,
    const short* __restrict__ kh, const short* __restrict__ vht,
    const float* __restrict__ P, short* __restrict__ attn_out,
    float* __restrict__ pacc, float* __restrict__ pms, int ntiles)
{
    __shared__ __align__(16) float Sraw[16 * SRAW_SLAB];   // [h][l][20] 20480 B
    __shared__ __align__(16) char  UPool[8 * 2 * 64 * VS_PITCH * 2];  // 49152 B union
    __shared__ float PmS[256];                             // 1024 B (total 70656)

    float* Smix  = (float*)UPool;                          // [m][l][20] f32 (20480 B)
    const int tid  = threadIdx.x;
    const int n    = blockIdx.x;
    const int half = n >> 8;
    const int inr  = n & 255;
    const int b    = (inr >> 2) & 1;                       // XCD swizzle
    const int l0   = ((inr >> 3) * 4 + (inr & 3)) * 16;
    const int tb   = half * ntiles;                        // first m-tile
    const int w    = tid >> 6, lane = tid & 63;
    const int l16  = lane & 15, qq = lane >> 4;
    const size_t hb = (size_t)b * H_;
    short* VslabW = (short*)UPool + w * (2 * 64 * VS_PITCH);  // per-wave 6144 B

    // ---- Q frags (persistent)
    bf16x8 qf[2][2][2];
    #pragma unroll
    for (int hh = 0; hh < 2; ++hh)
        #pragma unroll
        for (int kc = 0; kc < 2; ++kc) {
            size_t off = ((hb + 2 * w + hh) * L_ + l0 + l16) * HD_ + kc * 32 + qq * 8;
            qf[hh][kc][0] = *(const bf16x8*)(qh  + off);
            qf[hh][kc][1] = *(const bf16x8*)(qlo + off);
        }

    // V^T staging mapping
    int vgi_[4], vd_[4];
    const int vc = lane & 1;
    #pragma unroll
    for (int i = 0; i < 4; ++i) {
        int vrow = i * 32 + (lane >> 1);
        vgi_[i] = vrow >> 6;
        vd_[i]  = vrow & 63;
    }
    int vwoff[4];
    #pragma unroll
    for (int i = 0; i < 4; ++i)
        vwoff[i] = vgi_[i] * (64 * VS_PITCH) + vd_[i] * VS_PITCH + vc * 8;

    auto kload = [&](int tile, bf16x8 (&kdst)[2][2]) {
        const int mn = (tile & 127) * 16;
        #pragma unroll
        for (int hh = 0; hh < 2; ++hh)
            #pragma unroll
            for (int kc = 0; kc < 2; ++kc)
                kdst[hh][kc] = *(const bf16x8*)(kh + ((hb + 2 * w + hh) * L_ + mn + l16) * HD_ + kc * 32 + qq * 8);
    };
    auto vload = [&](int tile, bf16x8 (&vdst)[4]) {
        const int mn = (tile & 127) * 16;
        #pragma unroll
        for (int i = 0; i < 4; ++i)
            vdst[i] = *(const bf16x8*)(vht + ((hb + 2 * w + vgi_[i]) * HD_ + vd_[i]) * (size_t)L_ + mn + vc * 8);
    };

    bf16x8 kP[2][2], vst[4];
    kload(tb, kP); vload(tb, vst);

    if (tid < 256) PmS[tid] = P[tid] * 0.125f;            // fold 1/sqrt(64)

    f32x4 acc[2][4];
    #pragma unroll
    for (int dt = 0; dt < 4; ++dt) { acc[0][dt] = (f32x4){0.f,0.f,0.f,0.f}; acc[1][dt] = (f32x4){0.f,0.f,0.f,0.f}; }
    float mrun0 = 0.f, mrun1 = 0.f, srun0 = 0.f, srun1 = 0.f;   // deferred-max

    // QK^T: D[m][l], col=l16, rows m=qq*4+j.  One b128 write per head.
    auto qkt = [&](bf16x8 (&kr)[2][2], float* sb) {
        #pragma unroll
        for (int hh = 0; hh < 2; ++hh) {
            f32x4 s = (f32x4){0.f,0.f,0.f,0.f};
            s = __builtin_amdgcn_mfma_f32_16x16x32_bf16(kr[hh][0], qf[hh][0][0], s, 0, 0, 0);
            s = __builtin_amdgcn_mfma_f32_16x16x32_bf16(kr[hh][0], qf[hh][0][1], s, 0, 0, 0);
            s = __builtin_amdgcn_mfma_f32_16x16x32_bf16(kr[hh][1], qf[hh][1][0], s, 0, 0, 0);
            s = __builtin_amdgcn_mfma_f32_16x16x32_bf16(kr[hh][1], qf[hh][1][1], s, 0, 0, 0);
            *(f32x4*)(sb + ((2 * w + hh) * 16 + l16) * SRAW_PITCH + qq * 4) = s;
        }
    };

    // prologue: QK^T(tile tb) -> Sraw, publish (also PmS)
    qkt(kP, Sraw);
    block_sync();
    kload(tb + 1, kP);

    bf16x4 PAhi, PAlo;
    {
        float p0 = PmS[(qq * 4 + 0) * 16 + l16];
        float p1 = PmS[(qq * 4 + 1) * 16 + l16];
        float p2 = PmS[(qq * 4 + 2) * 16 + l16];
        float p3 = PmS[(qq * 4 + 3) * 16 + l16];
        PAhi = (bf16x4){ f2bf(p0), f2bf(p1), f2bf(p2), f2bf(p3) };
        PAlo = (bf16x4){ f2bf(p0 - bf2f(PAhi[0])), f2bf(p1 - bf2f(PAhi[1])),
                         f2bf(p2 - bf2f(PAhi[2])), f2bf(p3 - bf2f(PAhi[3])) };
    }

    for (int t = 0; t < ntiles; ++t) {
        // 1. mix via MFMA: gather paired m (float2, 4x b64) -> both mi chains
        {
            float2 g0 = *(const float2*)&Sraw[((qq * 4 + 0) * 16 + l16) * SRAW_PITCH + 2 * w];
            float2 g1 = *(const float2*)&Sraw[((qq * 4 + 1) * 16 + l16) * SRAW_PITCH + 2 * w];
            float2 g2 = *(const float2*)&Sraw[((qq * 4 + 2) * 16 + l16) * SRAW_PITCH + 2 * w];
            float2 g3 = *(const float2*)&Sraw[((qq * 4 + 3) * 16 + l16) * SRAW_PITCH + 2 * w];
            #pragma unroll
            for (int mi = 0; mi < 2; ++mi) {
                const int m = 2 * w + mi;
                float sv0 = mi ? g0.y : g0.x;
                float sv1 = mi ? g1.y : g1.x;
                float sv2 = mi ? g2.y : g2.x;
                float sv3 = mi ? g3.y : g3.x;
                bf16x4 bhi = { f2bf(sv0), f2bf(sv1), f2bf(sv2), f2bf(sv3) };
                bf16x4 blo = { f2bf(sv0 - bf2f(bhi[0])), f2bf(sv1 - bf2f(bhi[1])),
                               f2bf(sv2 - bf2f(bhi[2])), f2bf(sv3 - bf2f(bhi[3])) };
                f32x4 c = (f32x4){0.f, 0.f, 0.f, 0.f};
                c = __builtin_amdgcn_mfma_f32_16x16x16bf16_1k(PAhi, bhi, c, 0, 0, 0);
                c = __builtin_amdgcn_mfma_f32_16x16x16bf16_1k(PAhi, blo, c, 0, 0, 0);
                c = __builtin_amdgcn_mfma_f32_16x16x16bf16_1k(PAlo, bhi, c, 0, 0, 0);
                *(f32x4*)(Smix + (m * 16 + l16) * SRAW_PITCH + qq * 4) = c;
            }
        }
        block_sync();   // B_mid: Smix visible; mix-reads of Sraw done
        // 2. QK^T(tile tb+t+1) -> Sraw (safe: all mix-reads complete)
        qkt(kP, Sraw);
        kload(tb + t + 2, kP);
        // 3. softmax inputs from Smix: paired g (float2, 4x b64)
        float sx0[4], sx1[4];
        #pragma unroll
        for (int j = 0; j < 4; ++j) {
            float2 gg = *(const float2*)&Smix[((qq * 4 + j) * 16 + l16) * SRAW_PITCH + 2 * w];
            sx0[j] = gg.x;
            sx1[j] = gg.y;
        }
        // 4. deferred-max exps
        float e00 = __expf(sx0[0] - mrun0), e01 = __expf(sx0[1] - mrun0);
        float e02 = __expf(sx0[2] - mrun0), e03 = __expf(sx0[3] - mrun0);
        float e10 = __expf(sx1[0] - mrun1), e11 = __expf(sx1[1] - mrun1);
        float e12 = __expf(sx1[2] - mrun1), e13 = __expf(sx1[3] - mrun1);
        bf16x4 pf0 = { f2bf(e00), f2bf(e01), f2bf(e02), f2bf(e03) };
        bf16x4 pf1 = { f2bf(e10), f2bf(e11), f2bf(e12), f2bf(e13) };
        float t0r = fmaxf(fmaxf(sx0[0], sx0[1]), fmaxf(sx0[2], sx0[3]));
        float t1r = fmaxf(fmaxf(sx1[0], sx1[1]), fmaxf(sx1[2], sx1[3]));
        t0r = fmaxf(t0r, __shfl_xor(t0r, 16)); t0r = fmaxf(t0r, __shfl_xor(t0r, 32));
        t1r = fmaxf(t1r, __shfl_xor(t1r, 16)); t1r = fmaxf(t1r, __shfl_xor(t1r, 32));
        float ps0 = e00 + e01 + e02 + e03, ps1 = e10 + e11 + e12 + e13;
        ps0 += __shfl_xor(ps0, 16); ps0 += __shfl_xor(ps0, 32);
        ps1 += __shfl_xor(ps1, 16); ps1 += __shfl_xor(ps1, 32);
        block_sync();   // B_pv: ALL waves' Smix reads done -> union space free for V
        // 5. stage V (4x b128) + PV (same-wave slab, DS in-order)
        #pragma unroll
        for (int i = 0; i < 4; ++i)
            *(bf16x8*)&VslabW[vwoff[i]] = vst[i];
        #pragma unroll
        for (int i = 0; i < 2; ++i) {
            bf16x4 pf = i ? pf1 : pf0;
            #pragma unroll
            for (int dt = 0; dt < 4; ++dt) {
                bf16x4 afr = *(const bf16x4*)&VslabW[i * (64 * VS_PITCH) + (dt * 16 + l16) * VS_PITCH + qq * 4];
                acc[i][dt] = __builtin_amdgcn_mfma_f32_16x16x16bf16_1k(afr, pf, acc[i][dt], 0, 0, 0);
            }
        }
        // 6. V refill (vst dead after PV)
        vload(tb + t + 1, vst);
        // 7. rescale to new running max
        float mnew0 = fmaxf(mrun0, t0r), mnew1 = fmaxf(mrun1, t1r);
        float corr0 = __expf(mrun0 - mnew0), corr1 = __expf(mrun1 - mnew1);
        srun0 = (srun0 + ps0) * corr0; srun1 = (srun1 + ps1) * corr1;
        acc[0][0] *= corr0; acc[0][1] *= corr0; acc[0][2] *= corr0; acc[0][3] *= corr0;
        acc[1][0] *= corr1; acc[1][1] *= corr1; acc[1][2] *= corr1; acc[1][3] *= corr1;
        mrun0 = mnew0; mrun1 = mnew1;
        block_sync();   // B_end: Vslab reads done -> next mix may write Smix
    }

    if (pacc) {
        // partial epilogue: unnormalized acc + (m, s) per (g, l)
        #pragma unroll
        for (int i = 0; i < 2; ++i) {
            int g = 2 * w + i;
            #pragma unroll
            for (int dt = 0; dt < 4; ++dt)
                *(f32x4*)&pacc[(((size_t)n * 16 + g) * 16 + l16) * 64 + dt * 16 + qq * 4] = acc[i][dt];
        }
        if (qq == 0) {
            *(float2*)&pms[(((size_t)n * 16 + 2 * w)     * 16 + l16) * 2] = make_float2(mrun0, srun0);
            *(float2*)&pms[(((size_t)n * 16 + 2 * w + 1) * 16 + l16) * 2] = make_float2(mrun1, srun1);
        }
    } else {
        float inv0 = 1.f / srun0, inv1 = 1.f / srun1;
        #pragma unroll
        for (int i = 0; i < 2; ++i) {
            float inv = i ? inv1 : inv0;
            #pragma unroll
            for (int dt = 0; dt < 4; ++dt) {
                f32x4 a = acc[i][dt];
                bf16x4 ov = { f2bf(a[0] * inv), f2bf(a[1] * inv), f2bf(a[2] * inv), f2bf(a[3] * inv) };
                *(bf16x4*)(attn_out + ((size_t)(b * L_ + l0 + l16)) * D_ + (2 * w + i) * 64 + dt * 16 + qq * 4) = ov;
            }
        }
    }
}

// ---------------------------------------------------------------------------
// Kernel 2b: merge the 2 m-split partials -> bf16 attn.
// ---------------------------------------------------------------------------
__global__ __launch_bounds__(256) void merge_attn(
    const float* __restrict__ pacc, const float* __restrict__ pms,
    short* __restrict__ attn)
{
    const int cid = blockIdx.x * 256 + threadIdx.x;
    const int d4 = cid & 15;
    const int g  = (cid >> 4) & 15;
    const int l  = (cid >> 8) & (L_ - 1);
    const int b  = cid >> 19;
    const int lt = l >> 4, l16 = l & 15;
    const int n0 = ((lt >> 2) << 3) + (b << 2) + (lt & 3);
    const int n1 = n0 + 256;

    float2 ms0 = *(const float2*)&pms[(((size_t)n0 * 16 + g) * 16 + l16) * 2];
    float2 ms1 = *(const float2*)&pms[(((size_t)n1 * 16 + g) * 16 + l16) * 2];
    f32x4 o0 = *(const f32x4*)&pacc[(((size_t)n0 * 16 + g) * 16 + l16) * 64 + d4 * 4];
    f32x4 o1 = *(const f32x4*)&pacc[(((size_t)n1 * 16 + g) * 16 + l16) * 64 + d4 * 4];
    float Mx = fmaxf(ms0.x, ms1.x);
    float w0 = __expf(ms0.x - Mx), w1 = __expf(ms1.x - Mx);
    float s = ms0.y * w0 + ms1.y * w1;
    float inv = 1.f / s;
    f32x4 o = o0 * w0 + o1 * w1;
    bf16x4 ov = { f2bf(o[0] * inv), f2bf(o[1] * inv), f2bf(o[2] * inv), f2bf(o[3] * inv) };
    *(bf16x4*)(attn + ((size_t)(b * L_ + l) * D_) + g * 64 + d4 * 4) = ov;
}

// ---------------------------------------------------------------------------
// Kernel 3: output projection (attn bf16 @ Wo^T + bo) -> f32, MFMA.
// ---------------------------------------------------------------------------
__global__ __launch_bounds__(256) void out_mfma(
    const short* __restrict__ attn, const float* __restrict__ Wo,
    const float* __restrict__ bo, float* __restrict__ out)
{
    __shared__ short Ws[128][40];
    __shared__ short Xs[128][40];

    const int tid = threadIdx.x;
    const int w = tid >> 6, lane = tid & 63;
    const int l16 = lane & 15, qq = lane >> 4;
    const int m0 = blockIdx.x * 128;
    const int n0 = blockIdx.y * 128;
    const int ar0 = 64 * (w & 1);
    const int br0 = 64 * (w >> 1);

    f32x4 acc[4][4] = {};

    for (int k0 = 0; k0 < D_; k0 += 32) {
        #pragma unroll
        for (int i = 0; i < 4; ++i) {
            int fidx = i * 256 + tid;
            int r = fidx >> 3, c = fidx & 7;
            float4 wv4 = *(const float4*)(Wo + (size_t)(n0 + r) * D_ + k0 + c * 4);
            bf16x4 wb = { f2bf(wv4.x), f2bf(wv4.y), f2bf(wv4.z), f2bf(wv4.w) };
            *(bf16x4*)&Ws[r][c * 4] = wb;
        }
        #pragma unroll
        for (int i = 0; i < 2; ++i) {
            int cidx = i * 256 + tid;
            int r = cidx >> 2, c = cidx & 3;
            bf16x8 xv = *(const bf16x8*)(attn + (size_t)(m0 + r) * D_ + k0 + c * 8);
            *(bf16x8*)&Xs[r][c * 8] = xv;
        }
        __syncthreads();
        bf16x8 af[4], bfv[4];
        #pragma unroll
        for (int i = 0; i < 4; ++i) {
            af[i]  = *(const bf16x8*)&Ws[ar0 + 16 * i + l16][qq * 8];
            bfv[i] = *(const bf16x8*)&Xs[br0 + 16 * i + l16][qq * 8];
        }
        #pragma unroll
        for (int i = 0; i < 4; ++i)
            #pragma unroll
            for (int j = 0; j < 4; ++j)
                acc[i][j] = __builtin_amdgcn_mfma_f32_16x16x32_bf16(af[i], bfv[j], acc[i][j], 0, 0, 0);
        __syncthreads();
    }

    #pragma unroll
    for (int i = 0; i < 4; ++i) {
        int nb = n0 + ar0 + 16 * i + qq * 4;
        float4 b4 = *(const float4*)(bo + nb);
        #pragma unroll
        for (int j = 0; j < 4; ++j) {
            int m = m0 + br0 + 16 * j + l16;
            f32x4 c = acc[i][j];
            float4 ov = make_float4(c[0] + b4.x, c[1] + b4.y, c[2] + b4.z, c[3] + b4.w);
            *(float4*)&out[(size_t)m * D_ + nb] = ov;
        }
    }
}

// ---------------------------------------------------------------------------
extern "C" void kernel_launch(void* const* d_in, const int* in_sizes, int n_in,
                              void* d_out, int out_size, void* d_ws, size_t ws_size,
                              hipStream_t stream) {
    const float* q  = (const float*)d_in[0];
    const float* k  = (const float*)d_in[1];
    const float* v  = (const float*)d_in[2];
    const float* Wq = (const float*)d_in[3];
    const float* bq = (const float*)d_in[4];
    const float* Wk = (const float*)d_in[5];
    const float* bk = (const float*)d_in[6];
    const float* Wv = (const float*)d_in[7];
    const float* bv = (const float*)d_in[8];
    const float* Wo = (const float*)d_in[9];
    const float* bo = (const float*)d_in[10];
    const float* P  = (const float*)d_in[11];
    float* out = (float*)d_out;

    // ws: qh 8M | qlo 8M | kh 8M | vht 8M | attn 8M | pacc 32MiB | pms 1MiB
    char* ws = (char*)d_ws;
    short* qh   = (short*)(ws);
    short* qlo  = (short*)(ws + (size_t)8 * 1024 * 1024);
    short* kh   = (short*)(ws + (size_t)16 * 1024 * 1024);
    short* vht  = (short*)(ws + (size_t)24 * 1024 * 1024);
    short* attn = (short*)(ws + (size_t)32 * 1024 * 1024);
    float* pacc = (float*)(ws + (size_t)40 * 1024 * 1024);
    float* pms  = (float*)(ws + (size_t)40 * 1024 * 1024 + (size_t)512 * 16 * 16 * 64 * 4);
    const size_t need2 = (size_t)40 * 1024 * 1024
                       + (size_t)512 * 16 * 16 * 64 * 4    // pacc 32 MiB
                       + (size_t)512 * 16 * 16 * 2 * 4;    // pms 1 MiB
    const bool split2 = (ws_size >= need2);

    proj_mfma<<<dim3(M_ / 128, D_ / 128, 3), 256, 0, stream>>>(
        q, k, v, Wq, bq, Wk, bk, Wv, bv, qh, qlo, kh, vht);
    if (split2) {
        attn_mfma<<<dim3(512), 512, 0, stream>>>(qh, qlo, kh, vht, P, attn, pacc, pms, 64);
        merge_attn<<<dim3(4096), 256, 0, stream>>>(pacc, pms, attn);
    } else {
        attn_mfma<<<dim3(256), 512, 0, stream>>>(qh, qlo, kh, vht, P, attn, nullptr, nullptr, 128);
    }
    out_mfma<<<dim3(M_ / 128, D_ / 128), 256, 0, stream>>>(attn, Wo, bo, out);
}

// Round 17
// 357.553 us; speedup vs baseline: 1.3304x; 1.0550x over previous
//
#include <hip/hip_runtime.h>

#define D_  1024
#define H_  16
#define HD_ 64
#define L_  2048
#define B_  2
#define M_  (B_*L_)   // 4096 rows

typedef float f32x4  __attribute__((ext_vector_type(4)));
typedef short bf16x4 __attribute__((ext_vector_type(4)));
typedef short bf16x8 __attribute__((ext_vector_type(8)));

#define SRAW_PITCH 20   // f32 per l-row (80B, 16B-aligned -> b128 writes)
#define SRAW_SLAB  (16 * SRAW_PITCH)   // 320 f32 per h (or m) slab
#define VS_PITCH   24   // shorts per d-row (48B, 16B-aligned -> b128 stage)

__device__ __forceinline__ float bf2f(short s) {
    return __uint_as_float(((unsigned int)(unsigned short)s) << 16);
}
__device__ __forceinline__ short f2bf(float f) {   // RNE
    unsigned u = __float_as_uint(f);
    unsigned r = (u + 0x7FFFu + ((u >> 16) & 1u)) >> 16;
    return (short)r;
}
// Raw barrier: orders LDS (lgkmcnt(0) + "memory" clobber), does NOT drain vmcnt.
__device__ __forceinline__ void block_sync() {
    asm volatile("s_waitcnt lgkmcnt(0)" ::: "memory");
    __builtin_amdgcn_sched_barrier(0);
    __builtin_amdgcn_s_barrier();
    __builtin_amdgcn_sched_barrier(0);
}

// ---------------------------------------------------------------------------
// Kernel 1: QKV projections via bf16 MFMA. 128x128 tile, K-step 64 (R17:
// halves barrier count vs K32; accumulation order per acc[i][j] unchanged).
// z=0: q -> qh(hi)+qlo  [b][h][l][64]        (A=W rows n, B=X cols m: D[n][m])
// z=1: k -> kh          [b][h][l][64]        (same)
// z=2: v -> vht         [b][h][64][L]        (A=X rows m, B=W cols n: D[m][n])
// ---------------------------------------------------------------------------
__global__ __launch_bounds__(256) void proj_mfma(
    const float* __restrict__ q, const float* __restrict__ k, const float* __restrict__ v,
    const float* __restrict__ Wq, const float* __restrict__ bq,
    const float* __restrict__ Wk, const float* __restrict__ bk,
    const float* __restrict__ Wv, const float* __restrict__ bv,
    short* __restrict__ qh, short* __restrict__ qlo,
    short* __restrict__ kh, short* __restrict__ vht)
{
    const int z = blockIdx.z;
    const float* X    = (z == 0) ? q  : (z == 1) ? k  : v;
    const float* W    = (z == 0) ? Wq : (z == 1) ? Wk : Wv;
    const float* bias = (z == 0) ? bq : (z == 1) ? bk : bv;

    __shared__ short Ws[128][72];   // 64 data + 8 pad shorts (144B rows, 16B-aligned)
    __shared__ short Xs[128][72];

    const int tid  = threadIdx.x;
    const int w    = tid >> 6, lane = tid & 63;
    const int l16  = lane & 15, qq = lane >> 4;
    const int m0   = blockIdx.x * 128;
    const int n0   = blockIdx.y * 128;
    const int ar0  = 64 * (w & 1);
    const int br0  = 64 * (w >> 1);

    f32x4 acc[4][4] = {};

    for (int k0 = 0; k0 < D_; k0 += 64) {
        // stage: 128 rows x 64 cols per matrix; 2048 float4 chunks; 8/thread
        #pragma unroll
        for (int i = 0; i < 8; ++i) {
            int fidx = i * 256 + tid;
            int r = fidx >> 4, c = fidx & 15;
            float4 wv4 = *(const float4*)(W + (size_t)(n0 + r) * D_ + k0 + c * 4);
            float4 xv4 = *(const float4*)(X + (size_t)(m0 + r) * D_ + k0 + c * 4);
            bf16x4 wb = { f2bf(wv4.x), f2bf(wv4.y), f2bf(wv4.z), f2bf(wv4.w) };
            bf16x4 xb = { f2bf(xv4.x), f2bf(xv4.y), f2bf(xv4.z), f2bf(xv4.w) };
            *(bf16x4*)&Ws[r][c * 4] = wb;
            *(bf16x4*)&Xs[r][c * 4] = xb;
        }
        __syncthreads();
        bf16x8 af[2][4], bfv[2][4];
        #pragma unroll
        for (int kc = 0; kc < 2; ++kc)
            #pragma unroll
            for (int i = 0; i < 4; ++i) {
                const short* Ab = (z < 2) ? &Ws[ar0 + 16 * i + l16][kc * 32 + qq * 8]
                                          : &Xs[ar0 + 16 * i + l16][kc * 32 + qq * 8];
                const short* Bb = (z < 2) ? &Xs[br0 + 16 * i + l16][kc * 32 + qq * 8]
                                          : &Ws[br0 + 16 * i + l16][kc * 32 + qq * 8];
                af[kc][i]  = *(const bf16x8*)Ab;
                bfv[kc][i] = *(const bf16x8*)Bb;
            }
        #pragma unroll
        for (int kc = 0; kc < 2; ++kc)
            #pragma unroll
            for (int i = 0; i < 4; ++i)
                #pragma unroll
                for (int j = 0; j < 4; ++j)
                    acc[i][j] = __builtin_amdgcn_mfma_f32_16x16x32_bf16(af[kc][i], bfv[kc][j], acc[i][j], 0, 0, 0);
        __syncthreads();
    }

    if (z < 2) {
        #pragma unroll
        for (int i = 0; i < 4; ++i) {
            int nb = n0 + ar0 + 16 * i + qq * 4;
            float4 b4 = *(const float4*)(bias + nb);
            int h = nb >> 6, hd = nb & 63;
            #pragma unroll
            for (int j = 0; j < 4; ++j) {
                int m = m0 + br0 + 16 * j + l16;
                int bb = m >> 11, l = m & (L_ - 1);
                size_t o = ((((size_t)bb * H_ + h) * L_) + l) * HD_ + hd;
                f32x4 c = acc[i][j];
                float v0 = c[0] + b4.x, v1 = c[1] + b4.y, v2 = c[2] + b4.z, v3 = c[3] + b4.w;
                bf16x4 hi = { f2bf(v0), f2bf(v1), f2bf(v2), f2bf(v3) };
                if (z == 0) {
                    *(bf16x4*)&qh[o] = hi;
                    bf16x4 lo = { f2bf(v0 - bf2f(hi[0])), f2bf(v1 - bf2f(hi[1])),
                                  f2bf(v2 - bf2f(hi[2])), f2bf(v3 - bf2f(hi[3])) };
                    *(bf16x4*)&qlo[o] = lo;
                } else {
                    *(bf16x4*)&kh[o] = hi;
                }
            }
        }
    } else {
        // D[m][n]: rows m = m0+ar0+16i+4qq+r ; cols n = n0+br0+16j+l16
        #pragma unroll
        for (int i = 0; i < 4; ++i) {
            int mb = m0 + ar0 + 16 * i + qq * 4;
            int bb = mb >> 11, lb = mb & (L_ - 1);
            #pragma unroll
            for (int j = 0; j < 4; ++j) {
                int n = n0 + br0 + 16 * j + l16;
                int h = n >> 6, hd = n & 63;
                float bn = bias[n];
                size_t o = (((size_t)bb * H_ + h) * HD_ + hd) * (size_t)L_ + lb;
                f32x4 c = acc[i][j];
                bf16x4 ov = { f2bf(c[0] + bn), f2bf(c[1] + bn), f2bf(c[2] + bn), f2bf(c[3] + bn) };
                *(bf16x4*)&vht[o] = ov;
            }
        }
    }
}

// ---------------------------------------------------------------------------
// Kernel 2: fused talking-heads attention, m-SPLIT (flash split-K).
// (unchanged from R16 -- best verified attn at 277 us)
// ---------------------------------------------------------------------------
__global__ __launch_bounds__(512, 2) void attn_mfma(
    const short* __restrict__ qh, const short* __restrict__ qlo,
    const short* __restrict__ kh, const short* __restrict__ vht,
    const float* __restrict__ P, short* __restrict__ attn_out,
    float* __restrict__ pacc, float* __restrict__ pms, int ntiles)
{
    __shared__ __align__(16) float Sraw[16 * SRAW_SLAB];   // [h][l][20] 20480 B
    __shared__ __align__(16) char  UPool[8 * 2 * 64 * VS_PITCH * 2];  // 49152 B union
    __shared__ float PmS[256];                             // 1024 B (total 70656)

    float* Smix  = (float*)UPool;                          // [m][l][20] f32 (20480 B)
    const int tid  = threadIdx.x;
    const int n    = blockIdx.x;
    const int half = n >> 8;
    const int inr  = n & 255;
    const int b    = (inr >> 2) & 1;                       // XCD swizzle
    const int l0   = ((inr >> 3) * 4 + (inr & 3)) * 16;
    const int tb   = half * ntiles;                        // first m-tile
    const int w    = tid >> 6, lane = tid & 63;
    const int l16  = lane & 15, qq = lane >> 4;
    const size_t hb = (size_t)b * H_;
    short* VslabW = (short*)UPool + w * (2 * 64 * VS_PITCH);  // per-wave 6144 B

    // ---- Q frags (persistent)
    bf16x8 qf[2][2][2];
    #pragma unroll
    for (int hh = 0; hh < 2; ++hh)
        #pragma unroll
        for (int kc = 0; kc < 2; ++kc) {
            size_t off = ((hb + 2 * w + hh) * L_ + l0 + l16) * HD_ + kc * 32 + qq * 8;
            qf[hh][kc][0] = *(const bf16x8*)(qh  + off);
            qf[hh][kc][1] = *(const bf16x8*)(qlo + off);
        }

    // V^T staging mapping
    int vgi_[4], vd_[4];
    const int vc = lane & 1;
    #pragma unroll
    for (int i = 0; i < 4; ++i) {
        int vrow = i * 32 + (lane >> 1);
        vgi_[i] = vrow >> 6;
        vd_[i]  = vrow & 63;
    }
    int vwoff[4];
    #pragma unroll
    for (int i = 0; i < 4; ++i)
        vwoff[i] = vgi_[i] * (64 * VS_PITCH) + vd_[i] * VS_PITCH + vc * 8;

    auto kload = [&](int tile, bf16x8 (&kdst)[2][2]) {
        const int mn = (tile & 127) * 16;
        #pragma unroll
        for (int hh = 0; hh < 2; ++hh)
            #pragma unroll
            for (int kc = 0; kc < 2; ++kc)
                kdst[hh][kc] = *(const bf16x8*)(kh + ((hb + 2 * w + hh) * L_ + mn + l16) * HD_ + kc * 32 + qq * 8);
    };
    auto vload = [&](int tile, bf16x8 (&vdst)[4]) {
        const int mn = (tile & 127) * 16;
        #pragma unroll
        for (int i = 0; i < 4; ++i)
            vdst[i] = *(const bf16x8*)(vht + ((hb + 2 * w + vgi_[i]) * HD_ + vd_[i]) * (size_t)L_ + mn + vc * 8);
    };

    bf16x8 kP[2][2], vst[4];
    kload(tb, kP); vload(tb, vst);

    if (tid < 256) PmS[tid] = P[tid] * 0.125f;            // fold 1/sqrt(64)

    f32x4 acc[2][4];
    #pragma unroll
    for (int dt = 0; dt < 4; ++dt) { acc[0][dt] = (f32x4){0.f,0.f,0.f,0.f}; acc[1][dt] = (f32x4){0.f,0.f,0.f,0.f}; }
    float mrun0 = 0.f, mrun1 = 0.f, srun0 = 0.f, srun1 = 0.f;   // deferred-max

    // QK^T: D[m][l], col=l16, rows m=qq*4+j.  One b128 write per head.
    auto qkt = [&](bf16x8 (&kr)[2][2], float* sb) {
        #pragma unroll
        for (int hh = 0; hh < 2; ++hh) {
            f32x4 s = (f32x4){0.f,0.f,0.f,0.f};
            s = __builtin_amdgcn_mfma_f32_16x16x32_bf16(kr[hh][0], qf[hh][0][0], s, 0, 0, 0);
            s = __builtin_amdgcn_mfma_f32_16x16x32_bf16(kr[hh][0], qf[hh][0][1], s, 0, 0, 0);
            s = __builtin_amdgcn_mfma_f32_16x16x32_bf16(kr[hh][1], qf[hh][1][0], s, 0, 0, 0);
            s = __builtin_amdgcn_mfma_f32_16x16x32_bf16(kr[hh][1], qf[hh][1][1], s, 0, 0, 0);
            *(f32x4*)(sb + ((2 * w + hh) * 16 + l16) * SRAW_PITCH + qq * 4) = s;
        }
    };

    // prologue: QK^T(tile tb) -> Sraw, publish (also PmS)
    qkt(kP, Sraw);
    block_sync();
    kload(tb + 1, kP);

    bf16x4 PAhi, PAlo;
    {
        float p0 = PmS[(qq * 4 + 0) * 16 + l16];
        float p1 = PmS[(qq * 4 + 1) * 16 + l16];
        float p2 = PmS[(qq * 4 + 2) * 16 + l16];
        float p3 = PmS[(qq * 4 + 3) * 16 + l16];
        PAhi = (bf16x4){ f2bf(p0), f2bf(p1), f2bf(p2), f2bf(p3) };
        PAlo = (bf16x4){ f2bf(p0 - bf2f(PAhi[0])), f2bf(p1 - bf2f(PAhi[1])),
                         f2bf(p2 - bf2f(PAhi[2])), f2bf(p3 - bf2f(PAhi[3])) };
    }

    for (int t = 0; t < ntiles; ++t) {
        // 1. mix via MFMA: gather paired m (float2, 4x b64) -> both mi chains
        {
            float2 g0 = *(const float2*)&Sraw[((qq * 4 + 0) * 16 + l16) * SRAW_PITCH + 2 * w];
            float2 g1 = *(const float2*)&Sraw[((qq * 4 + 1) * 16 + l16) * SRAW_PITCH + 2 * w];
            float2 g2 = *(const float2*)&Sraw[((qq * 4 + 2) * 16 + l16) * SRAW_PITCH + 2 * w];
            float2 g3 = *(const float2*)&Sraw[((qq * 4 + 3) * 16 + l16) * SRAW_PITCH + 2 * w];
            #pragma unroll
            for (int mi = 0; mi < 2; ++mi) {
                const int m = 2 * w + mi;
                float sv0 = mi ? g0.y : g0.x;
                float sv1 = mi ? g1.y : g1.x;
                float sv2 = mi ? g2.y : g2.x;
                float sv3 = mi ? g3.y : g3.x;
                bf16x4 bhi = { f2bf(sv0), f2bf(sv1), f2bf(sv2), f2bf(sv3) };
                bf16x4 blo = { f2bf(sv0 - bf2f(bhi[0])), f2bf(sv1 - bf2f(bhi[1])),
                               f2bf(sv2 - bf2f(bhi[2])), f2bf(sv3 - bf2f(bhi[3])) };
                f32x4 c = (f32x4){0.f, 0.f, 0.f, 0.f};
                c = __builtin_amdgcn_mfma_f32_16x16x16bf16_1k(PAhi, bhi, c, 0, 0, 0);
                c = __builtin_amdgcn_mfma_f32_16x16x16bf16_1k(PAhi, blo, c, 0, 0, 0);
                c = __builtin_amdgcn_mfma_f32_16x16x16bf16_1k(PAlo, bhi, c, 0, 0, 0);
                *(f32x4*)(Smix + (m * 16 + l16) * SRAW_PITCH + qq * 4) = c;
            }
        }
        block_sync();   // B_mid: Smix visible; mix-reads of Sraw done
        // 2. QK^T(tile tb+t+1) -> Sraw (safe: all mix-reads complete)
        qkt(kP, Sraw);
        kload(tb + t + 2, kP);
        // 3. softmax inputs from Smix: paired g (float2, 4x b64)
        float sx0[4], sx1[4];
        #pragma unroll
        for (int j = 0; j < 4; ++j) {
            float2 gg = *(const float2*)&Smix[((qq * 4 + j) * 16 + l16) * SRAW_PITCH + 2 * w];
            sx0[j] = gg.x;
            sx1[j] = gg.y;
        }
        // 4. deferred-max exps
        float e00 = __expf(sx0[0] - mrun0), e01 = __expf(sx0[1] - mrun0);
        float e02 = __expf(sx0[2] - mrun0), e03 = __expf(sx0[3] - mrun0);
        float e10 = __expf(sx1[0] - mrun1), e11 = __expf(sx1[1] - mrun1);
        float e12 = __expf(sx1[2] - mrun1), e13 = __expf(sx1[3] - mrun1);
        bf16x4 pf0 = { f2bf(e00), f2bf(e01), f2bf(e02), f2bf(e03) };
        bf16x4 pf1 = { f2bf(e10), f2bf(e11), f2bf(e12), f2bf(e13) };
        float t0r = fmaxf(fmaxf(sx0[0], sx0[1]), fmaxf(sx0[2], sx0[3]));
        float t1r = fmaxf(fmaxf(sx1[0], sx1[1]), fmaxf(sx1[2], sx1[3]));
        t0r = fmaxf(t0r, __shfl_xor(t0r, 16)); t0r = fmaxf(t0r, __shfl_xor(t0r, 32));
        t1r = fmaxf(t1r, __shfl_xor(t1r, 16)); t1r = fmaxf(t1r, __shfl_xor(t1r, 32));
        float ps0 = e00 + e01 + e02 + e03, ps1 = e10 + e11 + e12 + e13;
        ps0 += __shfl_xor(ps0, 16); ps0 += __shfl_xor(ps0, 32);
        ps1 += __shfl_xor(ps1, 16); ps1 += __shfl_xor(ps1, 32);
        block_sync();   // B_pv: ALL waves' Smix reads done -> union space free for V
        // 5. stage V (4x b128) + PV (same-wave slab, DS in-order)
        #pragma unroll
        for (int i = 0; i < 4; ++i)
            *(bf16x8*)&VslabW[vwoff[i]] = vst[i];
        #pragma unroll
        for (int i = 0; i < 2; ++i) {
            bf16x4 pf = i ? pf1 : pf0;
            #pragma unroll
            for (int dt = 0; dt < 4; ++dt) {
                bf16x4 afr = *(const bf16x4*)&VslabW[i * (64 * VS_PITCH) + (dt * 16 + l16) * VS_PITCH + qq * 4];
                acc[i][dt] = __builtin_amdgcn_mfma_f32_16x16x16bf16_1k(afr, pf, acc[i][dt], 0, 0, 0);
            }
        }
        // 6. V refill (vst dead after PV)
        vload(tb + t + 1, vst);
        // 7. rescale to new running max
        float mnew0 = fmaxf(mrun0, t0r), mnew1 = fmaxf(mrun1, t1r);
        float corr0 = __expf(mrun0 - mnew0), corr1 = __expf(mrun1 - mnew1);
        srun0 = (srun0 + ps0) * corr0; srun1 = (srun1 + ps1) * corr1;
        acc[0][0] *= corr0; acc[0][1] *= corr0; acc[0][2] *= corr0; acc[0][3] *= corr0;
        acc[1][0] *= corr1; acc[1][1] *= corr1; acc[1][2] *= corr1; acc[1][3] *= corr1;
        mrun0 = mnew0; mrun1 = mnew1;
        block_sync();   // B_end: Vslab reads done -> next mix may write Smix
    }

    if (pacc) {
        // partial epilogue: unnormalized acc + (m, s) per (g, l)
        #pragma unroll
        for (int i = 0; i < 2; ++i) {
            int g = 2 * w + i;
            #pragma unroll
            for (int dt = 0; dt < 4; ++dt)
                *(f32x4*)&pacc[(((size_t)n * 16 + g) * 16 + l16) * 64 + dt * 16 + qq * 4] = acc[i][dt];
        }
        if (qq == 0) {
            *(float2*)&pms[(((size_t)n * 16 + 2 * w)     * 16 + l16) * 2] = make_float2(mrun0, srun0);
            *(float2*)&pms[(((size_t)n * 16 + 2 * w + 1) * 16 + l16) * 2] = make_float2(mrun1, srun1);
        }
    } else {
        float inv0 = 1.f / srun0, inv1 = 1.f / srun1;
        #pragma unroll
        for (int i = 0; i < 2; ++i) {
            float inv = i ? inv1 : inv0;
            #pragma unroll
            for (int dt = 0; dt < 4; ++dt) {
                f32x4 a = acc[i][dt];
                bf16x4 ov = { f2bf(a[0] * inv), f2bf(a[1] * inv), f2bf(a[2] * inv), f2bf(a[3] * inv) };
                *(bf16x4*)(attn_out + ((size_t)(b * L_ + l0 + l16)) * D_ + (2 * w + i) * 64 + dt * 16 + qq * 4) = ov;
            }
        }
    }
}

// ---------------------------------------------------------------------------
// Kernel 2b: merge the 2 m-split partials -> bf16 attn.
// ---------------------------------------------------------------------------
__global__ __launch_bounds__(256) void merge_attn(
    const float* __restrict__ pacc, const float* __restrict__ pms,
    short* __restrict__ attn)
{
    const int cid = blockIdx.x * 256 + threadIdx.x;
    const int d4 = cid & 15;
    const int g  = (cid >> 4) & 15;
    const int l  = (cid >> 8) & (L_ - 1);
    const int b  = cid >> 19;
    const int lt = l >> 4, l16 = l & 15;
    const int n0 = ((lt >> 2) << 3) + (b << 2) + (lt & 3);
    const int n1 = n0 + 256;

    float2 ms0 = *(const float2*)&pms[(((size_t)n0 * 16 + g) * 16 + l16) * 2];
    float2 ms1 = *(const float2*)&pms[(((size_t)n1 * 16 + g) * 16 + l16) * 2];
    f32x4 o0 = *(const f32x4*)&pacc[(((size_t)n0 * 16 + g) * 16 + l16) * 64 + d4 * 4];
    f32x4 o1 = *(const f32x4*)&pacc[(((size_t)n1 * 16 + g) * 16 + l16) * 64 + d4 * 4];
    float Mx = fmaxf(ms0.x, ms1.x);
    float w0 = __expf(ms0.x - Mx), w1 = __expf(ms1.x - Mx);
    float s = ms0.y * w0 + ms1.y * w1;
    float inv = 1.f / s;
    f32x4 o = o0 * w0 + o1 * w1;
    bf16x4 ov = { f2bf(o[0] * inv), f2bf(o[1] * inv), f2bf(o[2] * inv), f2bf(o[3] * inv) };
    *(bf16x4*)(attn + ((size_t)(b * L_ + l) * D_) + g * 64 + d4 * 4) = ov;
}

// ---------------------------------------------------------------------------
// Kernel 3: output projection (attn bf16 @ Wo^T + bo) -> f32, MFMA. K-step 64.
// ---------------------------------------------------------------------------
__global__ __launch_bounds__(256) void out_mfma(
    const short* __restrict__ attn, const float* __restrict__ Wo,
    const float* __restrict__ bo, float* __restrict__ out)
{
    __shared__ short Ws[128][72];
    __shared__ short Xs[128][72];

    const int tid = threadIdx.x;
    const int w = tid >> 6, lane = tid & 63;
    const int l16 = lane & 15, qq = lane >> 4;
    const int m0 = blockIdx.x * 128;
    const int n0 = blockIdx.y * 128;
    const int ar0 = 64 * (w & 1);
    const int br0 = 64 * (w >> 1);

    f32x4 acc[4][4] = {};

    for (int k0 = 0; k0 < D_; k0 += 64) {
        #pragma unroll
        for (int i = 0; i < 8; ++i) {
            int fidx = i * 256 + tid;
            int r = fidx >> 4, c = fidx & 15;
            float4 wv4 = *(const float4*)(Wo + (size_t)(n0 + r) * D_ + k0 + c * 4);
            bf16x4 wb = { f2bf(wv4.x), f2bf(wv4.y), f2bf(wv4.z), f2bf(wv4.w) };
            *(bf16x4*)&Ws[r][c * 4] = wb;
        }
        #pragma unroll
        for (int i = 0; i < 4; ++i) {
            int cidx = i * 256 + tid;
            int r = cidx >> 3, c = cidx & 7;
            bf16x8 xv = *(const bf16x8*)(attn + (size_t)(m0 + r) * D_ + k0 + c * 8);
            *(bf16x8*)&Xs[r][c * 8] = xv;
        }
        __syncthreads();
        bf16x8 af[2][4], bfv[2][4];
        #pragma unroll
        for (int kc = 0; kc < 2; ++kc)
            #pragma unroll
            for (int i = 0; i < 4; ++i) {
                af[kc][i]  = *(const bf16x8*)&Ws[ar0 + 16 * i + l16][kc * 32 + qq * 8];
                bfv[kc][i] = *(const bf16x8*)&Xs[br0 + 16 * i + l16][kc * 32 + qq * 8];
            }
        #pragma unroll
        for (int kc = 0; kc < 2; ++kc)
            #pragma unroll
            for (int i = 0; i < 4; ++i)
                #pragma unroll
                for (int j = 0; j < 4; ++j)
                    acc[i][j] = __builtin_amdgcn_mfma_f32_16x16x32_bf16(af[kc][i], bfv[kc][j], acc[i][j], 0, 0, 0);
        __syncthreads();
    }

    #pragma unroll
    for (int i = 0; i < 4; ++i) {
        int nb = n0 + ar0 + 16 * i + qq * 4;
        float4 b4 = *(const float4*)(bo + nb);
        #pragma unroll
        for (int j = 0; j < 4; ++j) {
            int m = m0 + br0 + 16 * j + l16;
            f32x4 c = acc[i][j];
            float4 ov = make_float4(c[0] + b4.x, c[1] + b4.y, c[2] + b4.z, c[3] + b4.w);
            *(float4*)&out[(size_t)m * D_ + nb] = ov;
        }
    }
}

// ---------------------------------------------------------------------------
extern "C" void kernel_launch(void* const* d_in, const int* in_sizes, int n_in,
                              void* d_out, int out_size, void* d_ws, size_t ws_size,
                              hipStream_t stream) {
    const float* q  = (const float*)d_in[0];
    const float* k  = (const float*)d_in[1];
    const float* v  = (const float*)d_in[2];
    const float* Wq = (const float*)d_in[3];
    const float* bq = (const float*)d_in[4];
    const float* Wk = (const float*)d_in[5];
    const float* bk = (const float*)d_in[6];
    const float* Wv = (const float*)d_in[7];
    const float* bv = (const float*)d_in[8];
    const float* Wo = (const float*)d_in[9];
    const float* bo = (const float*)d_in[10];
    const float* P  = (const float*)d_in[11];
    float* out = (float*)d_out;

    // ws: qh 8M | qlo 8M | kh 8M | vht 8M | attn 8M | pacc 32MiB | pms 1MiB
    char* ws = (char*)d_ws;
    short* qh   = (short*)(ws);
    short* qlo  = (short*)(ws + (size_t)8 * 1024 * 1024);
    short* kh   = (short*)(ws + (size_t)16 * 1024 * 1024);
    short* vht  = (short*)(ws + (size_t)24 * 1024 * 1024);
    short* attn = (short*)(ws + (size_t)32 * 1024 * 1024);
    float* pacc = (float*)(ws + (size_t)40 * 1024 * 1024);
    float* pms  = (float*)(ws + (size_t)40 * 1024 * 1024 + (size_t)512 * 16 * 16 * 64 * 4);
    const size_t need2 = (size_t)40 * 1024 * 1024
                       + (size_t)512 * 16 * 16 * 64 * 4    // pacc 32 MiB
                       + (size_t)512 * 16 * 16 * 2 * 4;    // pms 1 MiB
    const bool split2 = (ws_size >= need2);

    proj_mfma<<<dim3(M_ / 128, D_ / 128, 3), 256, 0, stream>>>(
        q, k, v, Wq, bq, Wk, bk, Wv, bv, qh, qlo, kh, vht);
    if (split2) {
        attn_mfma<<<dim3(512), 512, 0, stream>>>(qh, qlo, kh, vht, P, attn, pacc, pms, 64);
        merge_attn<<<dim3(4096), 256, 0, stream>>>(pacc, pms, attn);
    } else {
        attn_mfma<<<dim3(256), 512, 0, stream>>>(qh, qlo, kh, vht, P, attn, nullptr, nullptr, 128);
    }
    out_mfma<<<dim3(M_ / 128, D_ / 128), 256, 0, stream>>>(attn, Wo, bo, out);
}